// Round 10
// baseline (543.151 us; speedup 1.0000x reference)
//
#include <hip/hip_runtime.h>
#include <hip/hip_cooperative_groups.h>
#include <math.h>

namespace cg = cooperative_groups;

#define NN 2048
#define MM 50
#define CC 64
#define BB 64
#define EE 8192
#define NEG 0.2f
#define MARGIN_ 4.2f
#define ETILE 320
#define NB 512          // grid blocks; 33.8KB LDS -> 4 blocks/CU capacity, 512 co-resident w/ 2x margin

__global__ __launch_bounds__(256,4) void k_mega(
    const float* __restrict__ x, const float* __restrict__ w, const float* __restrict__ att,
    const int* __restrict__ nidx, const int* __restrict__ eidx,
    float* __restrict__ outf,
    float* __restrict__ natt1, float* __restrict__ natt2, float* __restrict__ eatt2,
    float* __restrict__ alpha, float* __restrict__ es, float* __restrict__ ef,
    float* __restrict__ nrm, float* __restrict__ pairl, float* __restrict__ rsBN,
    float* __restrict__ partial,
    int* __restrict__ ncnt, int* __restrict__ noff, int* __restrict__ ecnt,
    int* __restrict__ eoff, int* __restrict__ nlist, int* __restrict__ elist)
{
  cg::grid_group grid = cg::this_grid();
  int t = threadIdx.x;
  int bid = blockIdx.x;
  int wv = t>>6, lane = t&63;

  __shared__ union SM {
    struct { float Xl[64*68]; float Wl[4096]; } g;          // gemm: 33792 B
    struct { int e[ETILE]; int n[ETILE]; float al[ETILE*16]; } ed;  // edge: 23040 B
    struct { int n[ETILE]; float part[256]; } ea;           // eatt
    struct { float r1[256], r2[256], r3[256]; } lr;         // reductions
  } sm;

  // ================= P0a: CSR build (one wave per segment; fused offsets) ==========
  {
    unsigned long long ltmask = (1ull<<lane) - 1ull;
    for (int seg = bid*4+wv; seg < NN+MM; seg += NB*4){
      const int* key; int target; int* outl;
      if (seg < NN){ key=nidx; target=seg;    outl=nlist; }
      else         { key=eidx; target=seg-NN; outl=elist; }
      // offset = #incidences with key < target (== exclusive prefix of counts)
      int base = 0;
      for (int e=lane; e<EE; e+=64) base += (key[e] < target);
      #pragma unroll
      for (int m=32;m>=1;m>>=1) base += __shfl_xor(base,m,64);
      // stable ballot compaction
      int carry = 0;
      for (int wq=0; wq<EE/64; ++wq){
        int e = wq*64 + lane;
        bool mm = (key[e]==target);
        unsigned long long bal = __ballot(mm);
        if (mm) outl[base + carry + __popcll(bal & ltmask)] = e;
        carry += __popcll(bal);
      }
      if (lane==0){
        if (seg<NN){ ncnt[seg]=carry; noff[seg]=base; }
        else       { ecnt[seg-NN]=carry; eoff[seg-NN]=base; }
      }
    }
  }

  // ================= P0b: gemm xw = x@W (staged into outf) + natt1/natt2/rsBN ======
  {
    const float4* wsrc = (const float4*)w;
    for (int i=t;i<1024;i+=256) ((float4*)sm.g.Wl)[i] = wsrc[i];   // W once per block
    int rg = t>>4, cg4 = t&15;
    int c0 = cg4*4;
    float4 at1 = *(const float4*)(att + c0);
    float4 at2 = *(const float4*)(att + CC + c0);
    for (int tile=bid; tile<(NN*BB)/64; tile+=NB){
      size_t rbase = (size_t)tile*64;
      __syncthreads();                       // Wl ready / previous-iter readers done
      const float4* xs = (const float4*)(x + rbase*CC);
      #pragma unroll
      for (int i=0;i<4;++i){
        int idx = t + i*256;
        int r = idx>>4, c4 = idx&15;
        float4 v = xs[idx];
        *(float4*)&sm.g.Xl[r*68 + c4*4] = v;
      }
      __syncthreads();
      float acc[4][4];
      #pragma unroll
      for (int i=0;i<4;++i){ acc[i][0]=0.f; acc[i][1]=0.f; acc[i][2]=0.f; acc[i][3]=0.f; }
      #pragma unroll
      for (int ks=0; ks<16; ++ks){
        int k0 = ks*4;
        float4 Wf0 = *(const float4*)&sm.g.Wl[(k0+0)*64 + c0];
        float4 Wf1 = *(const float4*)&sm.g.Wl[(k0+1)*64 + c0];
        float4 Wf2 = *(const float4*)&sm.g.Wl[(k0+2)*64 + c0];
        float4 Wf3 = *(const float4*)&sm.g.Wl[(k0+3)*64 + c0];
        #pragma unroll
        for (int ri=0;ri<4;++ri){
          float4 Xf = *(const float4*)&sm.g.Xl[(rg*4+ri)*68 + k0];
          acc[ri][0] += Xf.x*Wf0.x; acc[ri][1] += Xf.x*Wf0.y; acc[ri][2] += Xf.x*Wf0.z; acc[ri][3] += Xf.x*Wf0.w;
          acc[ri][0] += Xf.y*Wf1.x; acc[ri][1] += Xf.y*Wf1.y; acc[ri][2] += Xf.y*Wf1.z; acc[ri][3] += Xf.y*Wf1.w;
          acc[ri][0] += Xf.z*Wf2.x; acc[ri][1] += Xf.z*Wf2.y; acc[ri][2] += Xf.z*Wf2.z; acc[ri][3] += Xf.z*Wf2.w;
          acc[ri][0] += Xf.w*Wf3.x; acc[ri][1] += Xf.w*Wf3.y; acc[ri][2] += Xf.w*Wf3.z; acc[ri][3] += Xf.w*Wf3.w;
        }
      }
      #pragma unroll
      for (int ri=0;ri<4;++ri){
        size_t row = rbase + rg*4 + ri;
        *(float4*)&outf[row*CC + c0] = make_float4(acc[ri][0],acc[ri][1],acc[ri][2],acc[ri][3]);
      }
      #pragma unroll
      for (int ri=0;ri<4;++ri){
        float a1 = acc[ri][0]*at1.x + acc[ri][1]*at1.y + acc[ri][2]*at1.z + acc[ri][3]*at1.w;
        float a2 = acc[ri][0]*at2.x + acc[ri][1]*at2.y + acc[ri][2]*at2.z + acc[ri][3]*at2.w;
        float rs = (acc[ri][0]+acc[ri][1]) + (acc[ri][2]+acc[ri][3]);
        #pragma unroll
        for (int m=8;m>=1;m>>=1){
          a1 += __shfl_xor(a1,m,64);
          a2 += __shfl_xor(a2,m,64);
          rs += __shfl_xor(rs,m,64);
        }
        if (cg4==0){
          size_t row = rbase + rg*4 + ri;
          int b = (int)(row>>11), n = (int)(row&(NN-1));
          natt1[n*BB+b]=a1; natt2[n*BB+b]=a2; rsBN[row]=rs;
        }
      }
    }
  }

  grid.sync();   // ---- build + gemm complete ----

  // ================= P1: eatt2[m,b] = sum_{e in m} natt2[node[e],b] ================
  for (int m=bid; m<MM; m+=NB){
    int b = t&63, ck = t>>6;
    int off=eoff[m], deg=ecnt[m];
    float s=0.f;
    for (int tb=0; tb<deg; tb+=ETILE){
      int tl = min(ETILE, deg-tb);
      __syncthreads();
      for (int j=t;j<tl;j+=256) sm.ea.n[j]=nidx[elist[off+tb+j]];
      __syncthreads();
      int j0=(tl*ck)>>2, j1=(tl*(ck+1))>>2;
      for (int j=j0;j<j1;++j) s += natt2[sm.ea.n[j]*BB+b];
    }
    sm.ea.part[t]=s; __syncthreads();
    if (t<64) eatt2[m*BB+b] = (sm.ea.part[b]+sm.ea.part[64+b])+(sm.ea.part[128+b]+sm.ea.part[192+b]);
    __syncthreads();
  }

  grid.sync();   // ---- eatt2 complete ----

  // ================= P2: grouped softmax per node (wave per node, lane = batch) ====
  for (int n = bid*4+wv; n < NN; n += NB*4){
    int off = noff[n], deg = ncnt[n];
    if (deg==0) continue;
    int b = lane;
    float na = natt1[n*BB+b];
    float mx = -1e30f;
    for (int j=0;j<deg;++j){
      int e = nlist[off+j]; int m = eidx[e];
      float l = na + eatt2[m*BB+b]; l = l>0.f? l : NEG*l;
      mx = fmaxf(mx,l);
    }
    float s=0.f;
    for (int j=0;j<deg;++j){
      int e = nlist[off+j]; int m = eidx[e];
      float l = na + eatt2[m*BB+b]; l = l>0.f? l : NEG*l;
      s += expf(l-mx);
    }
    float inv = 1.f/(s+1e-16f);
    for (int j=0;j<deg;++j){
      int e = nlist[off+j]; int m = eidx[e];
      float l = na + eatt2[m*BB+b]; l = l>0.f? l : NEG*l;
      alpha[(size_t)e*BB+b] = expf(l-mx)*inv;
    }
  }

  grid.sync();   // ---- alpha complete ----

  // ================= P3: per-edge gather: es, ef, nrm ==============================
  for (int mb=bid; mb<MM*4; mb+=NB){
    int m = mb>>2, bq = mb&3;
    int bi = t>>4;
    int b  = bq*16 + bi;
    int c0 = (t&15)*4;
    int off = eoff[m], deg = ecnt[m];
    float4 as=make_float4(0.f,0.f,0.f,0.f), af=as;
    for (int tb=0; tb<deg; tb+=ETILE){
      int tl = min(ETILE, deg-tb);
      __syncthreads();
      for (int j=t;j<tl;j+=256){
        int e = elist[off+tb+j];
        sm.ed.e[j]=e; sm.ed.n[j]=nidx[e];
      }
      __syncthreads();
      for (int idx=t; idx<tl*16; idx+=256){
        int j=idx>>4, b2=idx&15;
        sm.ed.al[idx] = alpha[(size_t)sm.ed.e[j]*BB + bq*16 + b2];
      }
      __syncthreads();
      #pragma unroll 4
      for (int j=0;j<tl;++j){
        int n = sm.ed.n[j];
        float al = sm.ed.al[j*16+bi];
        float4 v = *(const float4*)&outf[(size_t)b*(NN*CC) + (size_t)n*CC + c0];
        as.x+=v.x; as.y+=v.y; as.z+=v.z; as.w+=v.w;
        af.x+=al*v.x; af.y+=al*v.y; af.z+=al*v.z; af.w+=al*v.w;
      }
    }
    float bn = deg>0 ? 1.f/(float)deg : 0.f;
    size_t o = ((size_t)m*BB+b)*CC+c0;
    *(float4*)&es[o]=as;
    float4 f; f.x=af.x*bn; f.y=af.y*bn; f.z=af.z*bn; f.w=af.w*bn;
    *(float4*)&ef[o]=f;
    float ssq = as.x*as.x+as.y*as.y+as.z*as.z+as.w*as.w;
    #pragma unroll
    for (int s=8;s>=1;s>>=1) ssq += __shfl_xor(ssq,s,64);
    if ((t&15)==0) nrm[m*BB+b] = ssq>0.f? sqrtf(ssq):0.f;
    __syncthreads();
  }

  grid.sync();   // ---- es/ef/nrm complete ----

  // ================= P4a: pairwise loss (wave per (k,m) pair) ======================
  for (int km = bid*4+wv; km < MM*MM; km += NB*4){
    int kk = km / MM, m = km % MM;
    int b = lane;
    const float4* pa = (const float4*)&es[((size_t)kk*BB+b)*CC];
    const float4* pb = (const float4*)&es[((size_t)m*BB+b)*CC];
    float inner=0.f, d2=0.f;
    #pragma unroll
    for (int q=0;q<16;++q){
      float4 a=pa[q], c=pb[q];
      inner += a.x*c.x+a.y*c.y+a.z*c.z+a.w*c.w;
      float dx=a.x-c.x, dy=a.y-c.y, dz=a.z-c.z, dw=a.w-c.w;
      d2 += dx*dx+dy*dy+dz*dz+dw*dw;
    }
    float dist = d2>0.f? sqrtf(d2):0.f;
    float cosv = inner/(nrm[kk*BB+b]*nrm[m*BB+b]);
    float li = cosv*dist + (1.f-cosv)*fmaxf(MARGIN_-dist,0.f);
    #pragma unroll
    for (int s=32;s>=1;s>>=1) li += __shfl_xor(li,s,64);
    if (b==0) pairl[km] = fabsf(li*(1.f/64.f));
  }

  // ================= P4b: out (independent of pair; overwrites xw stage) ===========
  for (int n=bid; n<NN; n+=NB){
    int b = t>>2, sub = t&3;
    int off = noff[n], deg = ncnt[n];
    float4 a0=make_float4(0.f,0.f,0.f,0.f),a1=a0,a2=a0,a3=a0;
    for (int j=0;j<deg;++j){
      int e = nlist[off+j]; int m = eidx[e];
      float al = alpha[(size_t)e*BB+b];
      const float4* p = (const float4*)&ef[((size_t)m*BB+b)*CC + sub*16];
      float4 v0=p[0],v1=p[1],v2=p[2],v3=p[3];
      a0.x+=al*v0.x; a0.y+=al*v0.y; a0.z+=al*v0.z; a0.w+=al*v0.w;
      a1.x+=al*v1.x; a1.y+=al*v1.y; a1.z+=al*v1.z; a1.w+=al*v1.w;
      a2.x+=al*v2.x; a2.y+=al*v2.y; a2.z+=al*v2.z; a2.w+=al*v2.w;
      a3.x+=al*v3.x; a3.y+=al*v3.y; a3.z+=al*v3.z; a3.w+=al*v3.w;
    }
    float D=(float)deg;
    float* o = &outf[(size_t)b*(NN*CC) + (size_t)n*CC + sub*16];
    ((float4*)o)[0]=make_float4(D*a0.x,D*a0.y,D*a0.z,D*a0.w);
    ((float4*)o)[1]=make_float4(D*a1.x,D*a1.y,D*a1.z,D*a1.w);
    ((float4*)o)[2]=make_float4(D*a2.x,D*a2.y,D*a2.z,D*a2.w);
    ((float4*)o)[3]=make_float4(D*a3.x,D*a3.y,D*a3.z,D*a3.w);
  }

  grid.sync();   // ---- pairl complete ----

  // ================= P5: loss partials (NB blocks, fixed strided partition) ========
  {
    int gid = bid*256+t, stride = NB*256;
    float s1=0.f,s2=0.f,s3=0.f;
    for (int i=gid;i<MM*MM;i+=stride)    s1+=pairl[i];
    for (int i=gid;i<NN*BB;i+=stride)    s2+=rsBN[i]*(float)ncnt[i&(NN-1)];
    for (int i=gid;i<MM*BB*CC;i+=stride) s3+=es[i]*(float)ecnt[i>>12];
    sm.lr.r1[t]=s1; sm.lr.r2[t]=s2; sm.lr.r3[t]=s3; __syncthreads();
    for (int s=128;s>0;s>>=1){
      if(t<s){ sm.lr.r1[t]+=sm.lr.r1[t+s]; sm.lr.r2[t]+=sm.lr.r2[t+s]; sm.lr.r3[t]+=sm.lr.r3[t+s]; }
      __syncthreads();
    }
    if (t==0){
      partial[bid*3+0]=sm.lr.r1[0];
      partial[bid*3+1]=sm.lr.r2[0];
      partial[bid*3+2]=sm.lr.r3[0];
    }
  }

  grid.sync();   // ---- partials complete ----

  // ================= P6: final scalar (block 0) ====================================
  if (bid==0){
    sm.lr.r1[t] = partial[t*3+0] + partial[(t+256)*3+0];
    sm.lr.r2[t] = partial[t*3+1] + partial[(t+256)*3+1];
    sm.lr.r3[t] = partial[t*3+2] + partial[(t+256)*3+2];
    __syncthreads();
    for (int s=128;s>0;s>>=1){
      if(t<s){ sm.lr.r1[t]+=sm.lr.r1[t+s]; sm.lr.r2[t]+=sm.lr.r2[t+s]; sm.lr.r3[t]+=sm.lr.r3[t+s]; }
      __syncthreads();
    }
    if (t==0){
      float lh = sm.lr.r1[0]/2601.f;                            // /(M+1)^2
      float con = fabsf((sm.lr.r2[0]-sm.lr.r3[0])*(1.f/33554432.f)); // /(E*B*C)
      outf[(size_t)NN*BB*CC] = con+lh;
    }
  }
}

extern "C" void kernel_launch(void* const* d_in, const int* in_sizes, int n_in,
                              void* d_out, int out_size, void* d_ws, size_t ws_size,
                              hipStream_t stream){
  (void)in_sizes; (void)n_in; (void)out_size; (void)ws_size;
  const float* x    = (const float*)d_in[0];
  const float* w    = (const float*)d_in[1];
  const float* att  = (const float*)d_in[2];
  const int*   nidx = (const int*)d_in[3];
  const int*   eidx = (const int*)d_in[4];
  float* outf = (float*)d_out;

  char* ws = (char*)d_ws;
  size_t off = 0;
  auto alloc = [&](size_t bytes)->void*{ void* p = ws + off; off = (off + bytes + 255) & ~(size_t)255; return p; };
  float* natt1 = (float*)alloc(sizeof(float)*NN*BB);
  float* natt2 = (float*)alloc(sizeof(float)*NN*BB);
  float* eatt2 = (float*)alloc(sizeof(float)*MM*BB);
  float* alpha = (float*)alloc(sizeof(float)*(size_t)EE*BB);
  float* es    = (float*)alloc(sizeof(float)*MM*BB*CC);
  float* ef    = (float*)alloc(sizeof(float)*MM*BB*CC);
  float* nrm   = (float*)alloc(sizeof(float)*MM*BB);
  float* pairl = (float*)alloc(sizeof(float)*MM*MM);
  float* rsBN  = (float*)alloc(sizeof(float)*NN*BB);
  float* partial=(float*)alloc(sizeof(float)*NB*3);
  int* ncnt = (int*)alloc(sizeof(int)*NN);
  int* noff = (int*)alloc(sizeof(int)*NN);
  int* ecnt = (int*)alloc(sizeof(int)*MM);
  int* eoff = (int*)alloc(sizeof(int)*MM);
  int* nlist= (int*)alloc(sizeof(int)*EE);
  int* elist= (int*)alloc(sizeof(int)*EE);

  void* args[] = {
    (void*)&x, (void*)&w, (void*)&att, (void*)&nidx, (void*)&eidx,
    (void*)&outf,
    (void*)&natt1, (void*)&natt2, (void*)&eatt2, (void*)&alpha,
    (void*)&es, (void*)&ef, (void*)&nrm, (void*)&pairl, (void*)&rsBN,
    (void*)&partial,
    (void*)&ncnt, (void*)&noff, (void*)&ecnt, (void*)&eoff,
    (void*)&nlist, (void*)&elist
  };
  hipLaunchCooperativeKernel((const void*)k_mega, dim3(NB), dim3(256), args, 0, stream);
}

// Round 11
// 139.637 us; speedup vs baseline: 3.8897x; 3.8897x over previous
//
#include <hip/hip_runtime.h>
#include <math.h>

#define NN 2048
#define MM 50
#define CC 64
#define BB 64
#define EE 8192
#define NEG 0.2f
#define MARGIN_ 4.2f
#define ETILE 320
#define NPAIRBLK 625   // ceil(MM*MM/4)

// ---- CSR build with fused offsets: one wave per segment.
//      offset = #{e : key[e] < target}  (exclusive prefix of counts, order-free)
__global__ __launch_bounds__(256) void k_build(const int* __restrict__ nidx,const int* __restrict__ eidx,
                        int* __restrict__ ncnt,int* __restrict__ noff,
                        int* __restrict__ ecnt,int* __restrict__ eoff,
                        int* __restrict__ nlist,int* __restrict__ elist){
  int t=threadIdx.x, wv=t>>6, lane=t&63;
  int seg = blockIdx.x*4 + wv;
  if (seg >= NN+MM) return;
  const int* key; int target; int* outl;
  if (seg < NN){ key=nidx; target=seg;    outl=nlist; }
  else         { key=eidx; target=seg-NN; outl=elist; }
  int base = 0;
  for (int e=lane; e<EE; e+=64) base += (key[e] < target);
  #pragma unroll
  for (int m=32;m>=1;m>>=1) base += __shfl_xor(base,m,64);
  unsigned long long ltmask = (1ull<<lane) - 1ull;
  int carry = 0;
  for (int wq=0; wq<EE/64; ++wq){
    int e = wq*64 + lane;
    bool mm = (key[e]==target);
    unsigned long long bal = __ballot(mm);
    if (mm) outl[base + carry + __popcll(bal & ltmask)] = e;
    carry += __popcll(bal);
  }
  if (lane==0){
    if (seg<NN){ ncnt[seg]=carry; noff[seg]=base; }
    else       { ecnt[seg-NN]=carry; eoff[seg-NN]=base; }
  }
}

// ---- xw = x @ W : register-tiled 4x4, LDS-staged X(+pad)/W. Fuses natt1/natt2
//      and the s2 loss partial (sum rs*ncnt[n] per block -> gpart2).
__global__ __launch_bounds__(256) void k_gemm(const float* __restrict__ x,const float* __restrict__ w,
       const float* __restrict__ att, float* __restrict__ outf,
       float* __restrict__ natt1,float* __restrict__ natt2,
       const int* __restrict__ ncnt, float* __restrict__ gpart2){
  __shared__ float Xl[64*68];
  __shared__ float Wl[64*64];
  __shared__ float red[16];
  int t = threadIdx.x;
  size_t rbase = (size_t)blockIdx.x*64;
  {
    const float4* xs = (const float4*)(x + rbase*CC);
    const float4* wsrc = (const float4*)w;
    #pragma unroll
    for (int i=0;i<4;++i){
      int idx = t + i*256;
      int r = idx>>4, c4 = idx&15;
      float4 v = xs[idx];
      *(float4*)&Xl[r*68 + c4*4] = v;
      ((float4*)Wl)[idx] = wsrc[idx];
    }
  }
  __syncthreads();
  int rg = t>>4, cg = t&15;
  int c0 = cg*4;
  float acc[4][4];
  #pragma unroll
  for (int i=0;i<4;++i){ acc[i][0]=0.f; acc[i][1]=0.f; acc[i][2]=0.f; acc[i][3]=0.f; }
  #pragma unroll
  for (int ks=0; ks<16; ++ks){
    int k0 = ks*4;
    float4 Wf0 = *(const float4*)&Wl[(k0+0)*64 + c0];
    float4 Wf1 = *(const float4*)&Wl[(k0+1)*64 + c0];
    float4 Wf2 = *(const float4*)&Wl[(k0+2)*64 + c0];
    float4 Wf3 = *(const float4*)&Wl[(k0+3)*64 + c0];
    #pragma unroll
    for (int ri=0;ri<4;++ri){
      float4 Xf = *(const float4*)&Xl[(rg*4+ri)*68 + k0];
      acc[ri][0] += Xf.x*Wf0.x; acc[ri][1] += Xf.x*Wf0.y; acc[ri][2] += Xf.x*Wf0.z; acc[ri][3] += Xf.x*Wf0.w;
      acc[ri][0] += Xf.y*Wf1.x; acc[ri][1] += Xf.y*Wf1.y; acc[ri][2] += Xf.y*Wf1.z; acc[ri][3] += Xf.y*Wf1.w;
      acc[ri][0] += Xf.z*Wf2.x; acc[ri][1] += Xf.z*Wf2.y; acc[ri][2] += Xf.z*Wf2.z; acc[ri][3] += Xf.z*Wf2.w;
      acc[ri][0] += Xf.w*Wf3.x; acc[ri][1] += Xf.w*Wf3.y; acc[ri][2] += Xf.w*Wf3.z; acc[ri][3] += Xf.w*Wf3.w;
    }
  }
  #pragma unroll
  for (int ri=0;ri<4;++ri){
    size_t row = rbase + rg*4 + ri;
    *(float4*)&outf[row*CC + c0] = make_float4(acc[ri][0],acc[ri][1],acc[ri][2],acc[ri][3]);
  }
  float4 at1 = *(const float4*)(att + c0);
  float4 at2 = *(const float4*)(att + CC + c0);
  float prs = 0.f;
  #pragma unroll
  for (int ri=0;ri<4;++ri){
    float a1 = acc[ri][0]*at1.x + acc[ri][1]*at1.y + acc[ri][2]*at1.z + acc[ri][3]*at1.w;
    float a2 = acc[ri][0]*at2.x + acc[ri][1]*at2.y + acc[ri][2]*at2.z + acc[ri][3]*at2.w;
    float rs = (acc[ri][0]+acc[ri][1]) + (acc[ri][2]+acc[ri][3]);
    #pragma unroll
    for (int m=8;m>=1;m>>=1){
      a1 += __shfl_xor(a1,m,64);
      a2 += __shfl_xor(a2,m,64);
      rs += __shfl_xor(rs,m,64);
    }
    if (cg==0){
      size_t row = rbase + rg*4 + ri;
      int b = (int)(row>>11), n = (int)(row&(NN-1));
      natt1[n*BB+b]=a1; natt2[n*BB+b]=a2;
      prs += rs*(float)ncnt[n];
    }
  }
  if (cg==0) red[rg] = prs;
  __syncthreads();
  if (t==0){
    float s=0.f;
    #pragma unroll
    for (int i=0;i<16;++i) s += red[i];
    gpart2[blockIdx.x] = s;
  }
}

// ---- eatt2[m,b] = sum_{e in m} natt2[node[e],b]  -- LDS-staged, 4-chunk ILP
__global__ __launch_bounds__(256) void k_eatt(const int* __restrict__ elist,const int* __restrict__ eoff,
                       const int* __restrict__ ecnt,const int* __restrict__ nidx,
                       const float* __restrict__ natt2,float* __restrict__ eatt2){
  __shared__ int lds_n[ETILE];
  __shared__ float part[256];
  int m=blockIdx.x, t=threadIdx.x;
  int b = t&63, ck = t>>6;
  int off=eoff[m], deg=ecnt[m];
  float s=0.f;
  for (int tb=0; tb<deg; tb+=ETILE){
    int tl = min(ETILE, deg-tb);
    __syncthreads();
    for (int j=t;j<tl;j+=256) lds_n[j]=nidx[elist[off+tb+j]];
    __syncthreads();
    int j0=(tl*ck)>>2, j1=(tl*(ck+1))>>2;
    for (int j=j0;j<j1;++j) s += natt2[lds_n[j]*BB+b];
  }
  part[t]=s; __syncthreads();
  if (t<64) eatt2[m*BB+b] = (part[b]+part[64+b])+(part[128+b]+part[192+b]);
}

// ---- grouped softmax per node (1 wave per node, lane = batch)
__global__ void k_alpha(const int* __restrict__ nlist,const int* __restrict__ noff,
                        const int* __restrict__ ncnt,const int* __restrict__ eidx,
                        const float* __restrict__ natt1,const float* __restrict__ eatt2,
                        float* __restrict__ alpha){
  int n = blockIdx.x, b = threadIdx.x;
  int off = noff[n], deg = ncnt[n];
  if (deg==0) return;
  float na = natt1[n*BB+b];
  float mx = -1e30f;
  for (int j=0;j<deg;++j){
    int e = nlist[off+j]; int m = eidx[e];
    float l = na + eatt2[m*BB+b]; l = l>0.f? l : NEG*l;
    mx = fmaxf(mx,l);
  }
  float s=0.f;
  for (int j=0;j<deg;++j){
    int e = nlist[off+j]; int m = eidx[e];
    float l = na + eatt2[m*BB+b]; l = l>0.f? l : NEG*l;
    s += expf(l-mx);
  }
  float inv = 1.f/(s+1e-16f);
  for (int j=0;j<deg;++j){
    int e = nlist[off+j]; int m = eidx[e];
    float l = na + eatt2[m*BB+b]; l = l>0.f? l : NEG*l;
    alpha[(size_t)e*BB+b] = expf(l-mx)*inv;
  }
}

// ---- fused per-edge gather: es, ef, nrm + s3 loss partial (sum es * deg per block)
__global__ __launch_bounds__(256) void k_edge(const int* __restrict__ elist,const int* __restrict__ eoff,
                       const int* __restrict__ ecnt,const int* __restrict__ nidx,
                       const float* __restrict__ outf,const float* __restrict__ alpha,
                       float* __restrict__ es,float* __restrict__ ef,float* __restrict__ nrm,
                       float* __restrict__ gpart3){
  __shared__ int   lds_e[ETILE];
  __shared__ int   lds_n[ETILE];
  __shared__ float lds_al[ETILE*16];
  __shared__ float red2[256];
  int m = blockIdx.x>>2, bq = blockIdx.x&3;
  int t = threadIdx.x;
  int bi = t>>4;
  int b  = bq*16 + bi;
  int c0 = (t&15)*4;
  int off = eoff[m], deg = ecnt[m];
  float4 as=make_float4(0.f,0.f,0.f,0.f), af=as;
  for (int tb=0; tb<deg; tb+=ETILE){
    int tl = min(ETILE, deg-tb);
    __syncthreads();
    for (int j=t;j<tl;j+=256){
      int e = elist[off+tb+j];
      lds_e[j]=e; lds_n[j]=nidx[e];
    }
    __syncthreads();
    for (int idx=t; idx<tl*16; idx+=256){
      int j=idx>>4, b2=idx&15;
      lds_al[idx] = alpha[(size_t)lds_e[j]*BB + bq*16 + b2];
    }
    __syncthreads();
    #pragma unroll 4
    for (int j=0;j<tl;++j){
      int n = lds_n[j];
      float al = lds_al[j*16+bi];
      float4 v = *(const float4*)&outf[(size_t)b*(NN*CC) + (size_t)n*CC + c0];
      as.x+=v.x; as.y+=v.y; as.z+=v.z; as.w+=v.w;
      af.x+=al*v.x; af.y+=al*v.y; af.z+=al*v.z; af.w+=al*v.w;
    }
  }
  float bn = deg>0 ? 1.f/(float)deg : 0.f;
  size_t o = ((size_t)m*BB+b)*CC+c0;
  *(float4*)&es[o]=as;
  float4 f; f.x=af.x*bn; f.y=af.y*bn; f.z=af.z*bn; f.w=af.w*bn;
  *(float4*)&ef[o]=f;
  float ssq = as.x*as.x+as.y*as.y+as.z*as.z+as.w*as.w;
  #pragma unroll
  for (int s=8;s>=1;s>>=1) ssq += __shfl_xor(ssq,s,64);
  if ((t&15)==0) nrm[m*BB+b] = ssq>0.f? sqrtf(ssq):0.f;
  // s3 partial: sum of es over this block's chunk, x deg
  red2[t] = (as.x+as.y)+(as.z+as.w);
  __syncthreads();
  for (int s=128;s>0;s>>=1){ if(t<s) red2[t]+=red2[t+s]; __syncthreads(); }
  if (t==0) gpart3[blockIdx.x] = red2[0]*(float)deg;
}

// ---- pair loss (blocks [0,NPAIRBLK), wave per (k,m)) + out (blocks [NPAIRBLK,..))
__global__ __launch_bounds__(256) void k_pairout(const float* __restrict__ es,const float* __restrict__ nrm,
                      float* __restrict__ pairl,
                      const int* __restrict__ nlist,const int* __restrict__ noff,
                      const int* __restrict__ ncnt,const int* __restrict__ eidx,
                      const float* __restrict__ alpha,const float* __restrict__ ef,
                      float* __restrict__ outf){
  int bid = blockIdx.x;
  int t = threadIdx.x;
  if (bid < NPAIRBLK){
    int wv = t>>6, b = t&63;
    int km = bid*4 + wv;
    if (km < MM*MM){
      int kk = km / MM, m = km % MM;
      const float4* pa = (const float4*)&es[((size_t)kk*BB+b)*CC];
      const float4* pb = (const float4*)&es[((size_t)m*BB+b)*CC];
      float inner=0.f, d2=0.f;
      #pragma unroll
      for (int q=0;q<16;++q){
        float4 a=pa[q], c=pb[q];
        inner += a.x*c.x+a.y*c.y+a.z*c.z+a.w*c.w;
        float dx=a.x-c.x, dy=a.y-c.y, dz=a.z-c.z, dw=a.w-c.w;
        d2 += dx*dx+dy*dy+dz*dz+dw*dw;
      }
      float dist = d2>0.f? sqrtf(d2):0.f;
      float cosv = inner/(nrm[kk*BB+b]*nrm[m*BB+b]);
      float li = cosv*dist + (1.f-cosv)*fmaxf(MARGIN_-dist,0.f);
      #pragma unroll
      for (int s=32;s>=1;s>>=1) li += __shfl_xor(li,s,64);
      if (b==0) pairl[km] = fabsf(li*(1.f/64.f));
    }
    return;
  }
  int n = bid - NPAIRBLK;
  int b = t>>2, sub = t&3;
  int off = noff[n], deg = ncnt[n];
  float4 a0=make_float4(0.f,0.f,0.f,0.f),a1=a0,a2=a0,a3=a0;
  for (int j=0;j<deg;++j){
    int e = nlist[off+j]; int m = eidx[e];
    float al = alpha[(size_t)e*BB+b];
    const float4* p = (const float4*)&ef[((size_t)m*BB+b)*CC + sub*16];
    float4 v0=p[0],v1=p[1],v2=p[2],v3=p[3];
    a0.x+=al*v0.x; a0.y+=al*v0.y; a0.z+=al*v0.z; a0.w+=al*v0.w;
    a1.x+=al*v1.x; a1.y+=al*v1.y; a1.z+=al*v1.z; a1.w+=al*v1.w;
    a2.x+=al*v2.x; a2.y+=al*v2.y; a2.z+=al*v2.z; a2.w+=al*v2.w;
    a3.x+=al*v3.x; a3.y+=al*v3.y; a3.z+=al*v3.z; a3.w+=al*v3.w;
  }
  float D=(float)deg;
  float* o = &outf[(size_t)b*(NN*CC) + (size_t)n*CC + sub*16];
  ((float4*)o)[0]=make_float4(D*a0.x,D*a0.y,D*a0.z,D*a0.w);
  ((float4*)o)[1]=make_float4(D*a1.x,D*a1.y,D*a1.z,D*a1.w);
  ((float4*)o)[2]=make_float4(D*a2.x,D*a2.y,D*a2.z,D*a2.w);
  ((float4*)o)[3]=make_float4(D*a3.x,D*a3.y,D*a3.z,D*a3.w);
}

// ---- final scalar: one block reduces pairl + gpart2 + gpart3
__global__ void k_lfin(const float* __restrict__ pairl,const float* __restrict__ gpart2,
                       const float* __restrict__ gpart3, float* __restrict__ out){
  __shared__ float r1[256],r2[256],r3[256];
  int t=threadIdx.x;
  float s1=0.f,s2=0.f,s3=0.f;
  for (int i=t;i<MM*MM;i+=256) s1+=pairl[i];
  for (int i=t;i<(NN*BB)/64;i+=256) s2+=gpart2[i];
  for (int i=t;i<MM*4;i+=256) s3+=gpart3[i];
  r1[t]=s1;r2[t]=s2;r3[t]=s3; __syncthreads();
  for (int s=128;s>0;s>>=1){ if(t<s){r1[t]+=r1[t+s];r2[t]+=r2[t+s];r3[t]+=r3[t+s];} __syncthreads(); }
  if (t==0){
    float lh = r1[0]/2601.f;                           // /(M+1)^2
    float con = fabsf((r2[0]-r3[0])*(1.f/33554432.f)); // /(E*B*C)
    out[(size_t)NN*BB*CC] = con+lh;
  }
}

extern "C" void kernel_launch(void* const* d_in, const int* in_sizes, int n_in,
                              void* d_out, int out_size, void* d_ws, size_t ws_size,
                              hipStream_t stream){
  (void)in_sizes; (void)n_in; (void)out_size; (void)ws_size;
  const float* x    = (const float*)d_in[0];
  const float* w    = (const float*)d_in[1];
  const float* att  = (const float*)d_in[2];
  const int*   nidx = (const int*)d_in[3];
  const int*   eidx = (const int*)d_in[4];
  float* outf = (float*)d_out;

  char* ws = (char*)d_ws;
  size_t off = 0;
  auto alloc = [&](size_t bytes)->void*{ void* p = ws + off; off = (off + bytes + 255) & ~(size_t)255; return p; };
  float* natt1 = (float*)alloc(sizeof(float)*NN*BB);
  float* natt2 = (float*)alloc(sizeof(float)*NN*BB);
  float* eatt2 = (float*)alloc(sizeof(float)*MM*BB);
  float* alpha = (float*)alloc(sizeof(float)*(size_t)EE*BB);
  float* es    = (float*)alloc(sizeof(float)*MM*BB*CC);
  float* ef    = (float*)alloc(sizeof(float)*MM*BB*CC);
  float* nrm   = (float*)alloc(sizeof(float)*MM*BB);
  float* pairl = (float*)alloc(sizeof(float)*MM*MM);
  float* gpart2= (float*)alloc(sizeof(float)*(NN*BB)/64);
  float* gpart3= (float*)alloc(sizeof(float)*MM*4);
  int* ncnt = (int*)alloc(sizeof(int)*NN);
  int* noff = (int*)alloc(sizeof(int)*NN);
  int* ecnt = (int*)alloc(sizeof(int)*MM);
  int* eoff = (int*)alloc(sizeof(int)*MM);
  int* nlist= (int*)alloc(sizeof(int)*EE);
  int* elist= (int*)alloc(sizeof(int)*EE);

  k_build  <<<(NN+MM+3)/4, 256, 0, stream>>>(nidx, eidx, ncnt, noff, ecnt, eoff, nlist, elist);
  k_gemm   <<<(NN*BB)/64, 256, 0, stream>>>(x, w, att, outf, natt1, natt2, ncnt, gpart2);
  k_eatt   <<<MM, 256, 0, stream>>>(elist, eoff, ecnt, nidx, natt2, eatt2);
  k_alpha  <<<NN, 64, 0, stream>>>(nlist, noff, ncnt, eidx, natt1, eatt2, alpha);
  k_edge   <<<MM*4, 256, 0, stream>>>(elist, eoff, ecnt, nidx, outf, alpha, es, ef, nrm, gpart3);
  k_pairout<<<NPAIRBLK + NN, 256, 0, stream>>>(es, nrm, pairl, nlist, noff, ncnt, eidx, alpha, ef, outf);
  k_lfin   <<<1, 256, 0, stream>>>(pairl, gpart2, gpart3, outf);
}

// Round 12
// 136.402 us; speedup vs baseline: 3.9820x; 1.0237x over previous
//
#include <hip/hip_runtime.h>
#include <math.h>

#define NN 2048
#define MM 50
#define CC 64
#define BB 64
#define EE 8192
#define NEG 0.2f
#define MARGIN_ 4.2f
#define ETILE 320
#define NPAIRBLK 625      // ceil(MM*MM/4)
#define NBUILD 525        // ceil((NN+MM)/4)

// ================= K1: [CSR build || gemm] (independent block ranges) ============
__global__ __launch_bounds__(256) void k_bg(
    const float* __restrict__ x, const float* __restrict__ w, const float* __restrict__ att,
    const int* __restrict__ nidx, const int* __restrict__ eidx,
    float* __restrict__ outf, float* __restrict__ natt1, float* __restrict__ rsBN,
    int* __restrict__ ncnt, int* __restrict__ noff, int* __restrict__ ecnt,
    int* __restrict__ eoff, int* __restrict__ nlist, int* __restrict__ elist){
  __shared__ float Xl[64*68];
  __shared__ float Wl[64*64];
  int t = threadIdx.x;
  int bid = blockIdx.x;

  if (bid < NBUILD){
    // ---- build: one wave per segment; offset = #{key < target}
    int wv=t>>6, lane=t&63;
    int seg = bid*4 + wv;
    if (seg >= NN+MM) return;
    const int* key; int target; int* outl;
    if (seg < NN){ key=nidx; target=seg;    outl=nlist; }
    else         { key=eidx; target=seg-NN; outl=elist; }
    int base = 0;
    for (int e=lane; e<EE; e+=64) base += (key[e] < target);
    #pragma unroll
    for (int m=32;m>=1;m>>=1) base += __shfl_xor(base,m,64);
    unsigned long long ltmask = (1ull<<lane) - 1ull;
    int carry = 0;
    for (int wq=0; wq<EE/64; ++wq){
      int e = wq*64 + lane;
      bool mm = (key[e]==target);
      unsigned long long bal = __ballot(mm);
      if (mm) outl[base + carry + __popcll(bal & ltmask)] = e;
      carry += __popcll(bal);
    }
    if (lane==0){
      if (seg<NN){ ncnt[seg]=carry; noff[seg]=base; }
      else       { ecnt[seg-NN]=carry; eoff[seg-NN]=base; }
    }
    return;
  }

  // ---- gemm: register-tiled 4x4, LDS-staged X(+pad)/W; fuses natt1 + rsBN
  size_t rbase = (size_t)(bid - NBUILD)*64;
  {
    const float4* xs = (const float4*)(x + rbase*CC);
    const float4* wsrc = (const float4*)w;
    #pragma unroll
    for (int i=0;i<4;++i){
      int idx = t + i*256;
      int r = idx>>4, c4 = idx&15;
      float4 v = xs[idx];
      *(float4*)&Xl[r*68 + c4*4] = v;
      ((float4*)Wl)[idx] = wsrc[idx];
    }
  }
  __syncthreads();
  int rg = t>>4, cg = t&15;
  int c0 = cg*4;
  float acc[4][4];
  #pragma unroll
  for (int i=0;i<4;++i){ acc[i][0]=0.f; acc[i][1]=0.f; acc[i][2]=0.f; acc[i][3]=0.f; }
  #pragma unroll
  for (int ks=0; ks<16; ++ks){
    int k0 = ks*4;
    float4 Wf0 = *(const float4*)&Wl[(k0+0)*64 + c0];
    float4 Wf1 = *(const float4*)&Wl[(k0+1)*64 + c0];
    float4 Wf2 = *(const float4*)&Wl[(k0+2)*64 + c0];
    float4 Wf3 = *(const float4*)&Wl[(k0+3)*64 + c0];
    #pragma unroll
    for (int ri=0;ri<4;++ri){
      float4 Xf = *(const float4*)&Xl[(rg*4+ri)*68 + k0];
      acc[ri][0] += Xf.x*Wf0.x; acc[ri][1] += Xf.x*Wf0.y; acc[ri][2] += Xf.x*Wf0.z; acc[ri][3] += Xf.x*Wf0.w;
      acc[ri][0] += Xf.y*Wf1.x; acc[ri][1] += Xf.y*Wf1.y; acc[ri][2] += Xf.y*Wf1.z; acc[ri][3] += Xf.y*Wf1.w;
      acc[ri][0] += Xf.z*Wf2.x; acc[ri][1] += Xf.z*Wf2.y; acc[ri][2] += Xf.z*Wf2.z; acc[ri][3] += Xf.z*Wf2.w;
      acc[ri][0] += Xf.w*Wf3.x; acc[ri][1] += Xf.w*Wf3.y; acc[ri][2] += Xf.w*Wf3.z; acc[ri][3] += Xf.w*Wf3.w;
    }
  }
  #pragma unroll
  for (int ri=0;ri<4;++ri){
    size_t row = rbase + rg*4 + ri;
    *(float4*)&outf[row*CC + c0] = make_float4(acc[ri][0],acc[ri][1],acc[ri][2],acc[ri][3]);
  }
  float4 at1 = *(const float4*)(att + c0);
  #pragma unroll
  for (int ri=0;ri<4;++ri){
    float a1 = acc[ri][0]*at1.x + acc[ri][1]*at1.y + acc[ri][2]*at1.z + acc[ri][3]*at1.w;
    float rs = (acc[ri][0]+acc[ri][1]) + (acc[ri][2]+acc[ri][3]);
    #pragma unroll
    for (int m=8;m>=1;m>>=1){
      a1 += __shfl_xor(a1,m,64);
      rs += __shfl_xor(rs,m,64);
    }
    if (cg==0){
      size_t row = rbase + rg*4 + ri;
      int b = (int)(row>>11), n = (int)(row&(NN-1));
      natt1[n*BB+b]=a1; rsBN[row]=rs;
    }
  }
}

// ================= K2: [es/nrm/eatt2/gpart3 (200) || gpart2 partials (32)] =======
__global__ __launch_bounds__(256) void k_es(
    const int* __restrict__ elist,const int* __restrict__ eoff,
    const int* __restrict__ ecnt,const int* __restrict__ nidx,
    const float* __restrict__ outf,const float* __restrict__ att,
    float* __restrict__ es,float* __restrict__ nrm,float* __restrict__ eatt2,
    float* __restrict__ gpart3,
    const float* __restrict__ rsBN,const int* __restrict__ ncnt,
    float* __restrict__ gpart2){
  __shared__ int lds_n[ETILE];
  __shared__ float red2[256];
  int bid = blockIdx.x, t = threadIdx.x;

  if (bid >= MM*4){
    // ---- gpart2 partials: 32 blocks, fixed strided partition
    int k = bid - MM*4;
    float s = 0.f;
    for (int i=k*256+t; i<NN*BB; i+=32*256) s += rsBN[i]*(float)ncnt[i&(NN-1)];
    red2[t]=s; __syncthreads();
    for (int st=128;st>0;st>>=1){ if(t<st) red2[t]+=red2[t+st]; __syncthreads(); }
    if (t==0) gpart2[k]=red2[0];
    return;
  }

  int m = bid>>2, bq = bid&3;
  int bi = t>>4;
  int b  = bq*16 + bi;
  int c0 = (t&15)*4;
  int off = eoff[m], deg = ecnt[m];
  float4 as=make_float4(0.f,0.f,0.f,0.f);
  for (int tb=0; tb<deg; tb+=ETILE){
    int tl = min(ETILE, deg-tb);
    __syncthreads();
    for (int j=t;j<tl;j+=256) lds_n[j]=nidx[elist[off+tb+j]];
    __syncthreads();
    #pragma unroll 4
    for (int j=0;j<tl;++j){
      int n = lds_n[j];
      float4 v = *(const float4*)&outf[(size_t)b*(NN*CC) + (size_t)n*CC + c0];
      as.x+=v.x; as.y+=v.y; as.z+=v.z; as.w+=v.w;
    }
  }
  size_t o = ((size_t)m*BB+b)*CC+c0;
  *(float4*)&es[o]=as;
  // nrm + eatt2 (= es . att2) via 16-lane reduce
  float ssq = as.x*as.x+as.y*as.y+as.z*as.z+as.w*as.w;
  float4 at2 = *(const float4*)(att + CC + c0);
  float ea = as.x*at2.x+as.y*at2.y+as.z*at2.z+as.w*at2.w;
  #pragma unroll
  for (int s=8;s>=1;s>>=1){ ssq += __shfl_xor(ssq,s,64); ea += __shfl_xor(ea,s,64); }
  if ((t&15)==0){
    nrm[m*BB+b] = ssq>0.f? sqrtf(ssq):0.f;
    eatt2[m*BB+b] = ea;
  }
  // gpart3 partial: sum(es over block chunk) * deg
  red2[t] = (as.x+as.y)+(as.z+as.w);
  __syncthreads();
  for (int s=128;s>0;s>>=1){ if(t<s) red2[t]+=red2[t+s]; __syncthreads(); }
  if (t==0) gpart3[bid] = red2[0]*(float)deg;
}

// ================= K3: [pair (625) || alpha (512 x 4 waves)] =====================
__global__ __launch_bounds__(256) void k_ap(
    const float* __restrict__ es,const float* __restrict__ nrm,
    float* __restrict__ pairl,
    const int* __restrict__ nlist,const int* __restrict__ noff,
    const int* __restrict__ ncnt,const int* __restrict__ eidx,
    const float* __restrict__ natt1,const float* __restrict__ eatt2,
    float* __restrict__ alpha){
  int bid = blockIdx.x, t = threadIdx.x;
  int wv = t>>6, b = t&63;

  if (bid < NPAIRBLK){
    int km = bid*4 + wv;
    if (km >= MM*MM) return;
    int kk = km / MM, m = km % MM;
    const float4* pa = (const float4*)&es[((size_t)kk*BB+b)*CC];
    const float4* pb = (const float4*)&es[((size_t)m*BB+b)*CC];
    float inner=0.f, d2=0.f;
    #pragma unroll
    for (int q=0;q<16;++q){
      float4 a=pa[q], c=pb[q];
      inner += a.x*c.x+a.y*c.y+a.z*c.z+a.w*c.w;
      float dx=a.x-c.x, dy=a.y-c.y, dz=a.z-c.z, dw=a.w-c.w;
      d2 += dx*dx+dy*dy+dz*dz+dw*dw;
    }
    float dist = d2>0.f? sqrtf(d2):0.f;
    float cosv = inner/(nrm[kk*BB+b]*nrm[m*BB+b]);
    float li = cosv*dist + (1.f-cosv)*fmaxf(MARGIN_-dist,0.f);
    #pragma unroll
    for (int s=32;s>=1;s>>=1) li += __shfl_xor(li,s,64);
    if (b==0) pairl[km] = fabsf(li*(1.f/64.f));
    return;
  }

  int n = (bid - NPAIRBLK)*4 + wv;
  if (n >= NN) return;
  int off = noff[n], deg = ncnt[n];
  if (deg==0) return;
  float na = natt1[n*BB+b];
  float mx = -1e30f;
  for (int j=0;j<deg;++j){
    int e = nlist[off+j]; int m = eidx[e];
    float l = na + eatt2[m*BB+b]; l = l>0.f? l : NEG*l;
    mx = fmaxf(mx,l);
  }
  float s=0.f;
  for (int j=0;j<deg;++j){
    int e = nlist[off+j]; int m = eidx[e];
    float l = na + eatt2[m*BB+b]; l = l>0.f? l : NEG*l;
    s += expf(l-mx);
  }
  float inv = 1.f/(s+1e-16f);
  for (int j=0;j<deg;++j){
    int e = nlist[off+j]; int m = eidx[e];
    float l = na + eatt2[m*BB+b]; l = l>0.f? l : NEG*l;
    alpha[(size_t)e*BB+b] = expf(l-mx)*inv;
  }
}

// ================= K4: ef = (1/deg) sum alpha * xw (alpha-weighted gather) =======
__global__ __launch_bounds__(256) void k_ef(
    const int* __restrict__ elist,const int* __restrict__ eoff,
    const int* __restrict__ ecnt,const int* __restrict__ nidx,
    const float* __restrict__ outf,const float* __restrict__ alpha,
    float* __restrict__ ef){
  __shared__ int   lds_e[ETILE];
  __shared__ int   lds_n[ETILE];
  __shared__ float lds_al[ETILE*16];
  int m = blockIdx.x>>2, bq = blockIdx.x&3;
  int t = threadIdx.x;
  int bi = t>>4;
  int b  = bq*16 + bi;
  int c0 = (t&15)*4;
  int off = eoff[m], deg = ecnt[m];
  float4 af=make_float4(0.f,0.f,0.f,0.f);
  for (int tb=0; tb<deg; tb+=ETILE){
    int tl = min(ETILE, deg-tb);
    __syncthreads();
    for (int j=t;j<tl;j+=256){
      int e = elist[off+tb+j];
      lds_e[j]=e; lds_n[j]=nidx[e];
    }
    __syncthreads();
    for (int idx=t; idx<tl*16; idx+=256){
      int j=idx>>4, b2=idx&15;
      lds_al[idx] = alpha[(size_t)lds_e[j]*BB + bq*16 + b2];
    }
    __syncthreads();
    #pragma unroll 4
    for (int j=0;j<tl;++j){
      int n = lds_n[j];
      float al = lds_al[j*16+bi];
      float4 v = *(const float4*)&outf[(size_t)b*(NN*CC) + (size_t)n*CC + c0];
      af.x+=al*v.x; af.y+=al*v.y; af.z+=al*v.z; af.w+=al*v.w;
    }
  }
  float bn = deg>0 ? 1.f/(float)deg : 0.f;
  size_t o = ((size_t)m*BB+b)*CC+c0;
  float4 f; f.x=af.x*bn; f.y=af.y*bn; f.z=af.z*bn; f.w=af.w*bn;
  *(float4*)&ef[o]=f;
}

// ================= K5: [out (2048) || lfin (block NN)] ===========================
__global__ __launch_bounds__(256) void k_outl(
    const int* __restrict__ nlist,const int* __restrict__ noff,
    const int* __restrict__ ncnt,const int* __restrict__ eidx,
    const float* __restrict__ alpha,const float* __restrict__ ef,
    const float* __restrict__ pairl,const float* __restrict__ gpart2,
    const float* __restrict__ gpart3,
    float* __restrict__ outf){
  __shared__ float r1[256],r2[256],r3[256];
  int bid = blockIdx.x, t = threadIdx.x;

  if (bid == NN){
    float s1=0.f,s2=0.f,s3=0.f;
    for (int i=t;i<MM*MM;i+=256) s1+=pairl[i];
    if (t<32) s2=gpart2[t];
    for (int i=t;i<MM*4;i+=256) s3+=gpart3[i];
    r1[t]=s1;r2[t]=s2;r3[t]=s3; __syncthreads();
    for (int s=128;s>0;s>>=1){ if(t<s){r1[t]+=r1[t+s];r2[t]+=r2[t+s];r3[t]+=r3[t+s];} __syncthreads(); }
    if (t==0){
      float lh = r1[0]/2601.f;                           // /(M+1)^2
      float con = fabsf((r2[0]-r3[0])*(1.f/33554432.f)); // /(E*B*C)
      outf[(size_t)NN*BB*CC] = con+lh;
    }
    return;
  }

  int n = bid;
  int b = t>>2, sub = t&3;
  int off = noff[n], deg = ncnt[n];
  float4 a0=make_float4(0.f,0.f,0.f,0.f),a1=a0,a2=a0,a3=a0;
  for (int j=0;j<deg;++j){
    int e = nlist[off+j]; int m = eidx[e];
    float al = alpha[(size_t)e*BB+b];
    const float4* p = (const float4*)&ef[((size_t)m*BB+b)*CC + sub*16];
    float4 v0=p[0],v1=p[1],v2=p[2],v3=p[3];
    a0.x+=al*v0.x; a0.y+=al*v0.y; a0.z+=al*v0.z; a0.w+=al*v0.w;
    a1.x+=al*v1.x; a1.y+=al*v1.y; a1.z+=al*v1.z; a1.w+=al*v1.w;
    a2.x+=al*v2.x; a2.y+=al*v2.y; a2.z+=al*v2.z; a2.w+=al*v2.w;
    a3.x+=al*v3.x; a3.y+=al*v3.y; a3.z+=al*v3.z; a3.w+=al*v3.w;
  }
  float D=(float)deg;
  float* o = &outf[(size_t)b*(NN*CC) + (size_t)n*CC + sub*16];
  ((float4*)o)[0]=make_float4(D*a0.x,D*a0.y,D*a0.z,D*a0.w);
  ((float4*)o)[1]=make_float4(D*a1.x,D*a1.y,D*a1.z,D*a1.w);
  ((float4*)o)[2]=make_float4(D*a2.x,D*a2.y,D*a2.z,D*a2.w);
  ((float4*)o)[3]=make_float4(D*a3.x,D*a3.y,D*a3.z,D*a3.w);
}

extern "C" void kernel_launch(void* const* d_in, const int* in_sizes, int n_in,
                              void* d_out, int out_size, void* d_ws, size_t ws_size,
                              hipStream_t stream){
  (void)in_sizes; (void)n_in; (void)out_size; (void)ws_size;
  const float* x    = (const float*)d_in[0];
  const float* w    = (const float*)d_in[1];
  const float* att  = (const float*)d_in[2];
  const int*   nidx = (const int*)d_in[3];
  const int*   eidx = (const int*)d_in[4];
  float* outf = (float*)d_out;

  char* ws = (char*)d_ws;
  size_t off = 0;
  auto alloc = [&](size_t bytes)->void*{ void* p = ws + off; off = (off + bytes + 255) & ~(size_t)255; return p; };
  float* natt1 = (float*)alloc(sizeof(float)*NN*BB);
  float* eatt2 = (float*)alloc(sizeof(float)*MM*BB);
  float* alpha = (float*)alloc(sizeof(float)*(size_t)EE*BB);
  float* es    = (float*)alloc(sizeof(float)*MM*BB*CC);
  float* ef    = (float*)alloc(sizeof(float)*MM*BB*CC);
  float* nrm   = (float*)alloc(sizeof(float)*MM*BB);
  float* pairl = (float*)alloc(sizeof(float)*MM*MM);
  float* rsBN  = (float*)alloc(sizeof(float)*NN*BB);
  float* gpart2= (float*)alloc(sizeof(float)*32);
  float* gpart3= (float*)alloc(sizeof(float)*MM*4);
  int* ncnt = (int*)alloc(sizeof(int)*NN);
  int* noff = (int*)alloc(sizeof(int)*NN);
  int* ecnt = (int*)alloc(sizeof(int)*MM);
  int* eoff = (int*)alloc(sizeof(int)*MM);
  int* nlist= (int*)alloc(sizeof(int)*EE);
  int* elist= (int*)alloc(sizeof(int)*EE);

  k_bg  <<<NBUILD + (NN*BB)/64, 256, 0, stream>>>(x, w, att, nidx, eidx,
                                                  outf, natt1, rsBN,
                                                  ncnt, noff, ecnt, eoff, nlist, elist);
  k_es  <<<MM*4 + 32, 256, 0, stream>>>(elist, eoff, ecnt, nidx, outf, att,
                                        es, nrm, eatt2, gpart3, rsBN, ncnt, gpart2);
  k_ap  <<<NPAIRBLK + NN/4, 256, 0, stream>>>(es, nrm, pairl,
                                              nlist, noff, ncnt, eidx, natt1, eatt2, alpha);
  k_ef  <<<MM*4, 256, 0, stream>>>(elist, eoff, ecnt, nidx, outf, alpha, ef);
  k_outl<<<NN + 1, 256, 0, stream>>>(nlist, noff, ncnt, eidx, alpha, ef,
                                     pairl, gpart2, gpart3, outf);
}

// Round 13
// 128.188 us; speedup vs baseline: 4.2372x; 1.0641x over previous
//
#include <hip/hip_runtime.h>
#include <math.h>

#define NN 2048
#define MM 50
#define CC 64
#define BB 64
#define EE 8192
#define NEG 0.2f
#define MARGIN_ 4.2f
#define ETILE 320
#define NPAIRBLK 625      // ceil(MM*MM/4)
#define NSEG (NN+MM)      // build blocks: one per segment

// ================= K1: [CSR build (block/segment, 4-wave split) || gemm] =========
__global__ __launch_bounds__(256) void k_bg(
    const float* __restrict__ x, const float* __restrict__ w, const float* __restrict__ att,
    const int* __restrict__ nidx, const int* __restrict__ eidx,
    float* __restrict__ outf, float* __restrict__ natt1, float* __restrict__ rsBN,
    int* __restrict__ ncnt, int* __restrict__ noff, int* __restrict__ ecnt,
    int* __restrict__ eoff, int* __restrict__ nlist, int* __restrict__ elist){
  __shared__ float Xl[64*68];
  __shared__ float Wl[64*64];
  __shared__ int wcnt[4], wlt[4];
  int t = threadIdx.x;
  int bid = blockIdx.x;

  if (bid < NSEG){
    // ---- build: one block per segment; each wave scans a 2048-elem quarter of E.
    int seg = bid;
    const int* key; int target; int* outl;
    if (seg < NN){ key=nidx; target=seg;    outl=nlist; }
    else         { key=eidx; target=seg-NN; outl=elist; }
    int wv=t>>6, lane=t&63;
    int q0 = wv*2048;
    // pass 1: per-quarter counts of {==target} and {<target}
    int cm=0, cl=0;
    for (int i=lane; i<2048; i+=64){
      int k = key[q0+i];
      cm += (k==target); cl += (k<target);
    }
    #pragma unroll
    for (int m=32;m>=1;m>>=1){ cm += __shfl_xor(cm,m,64); cl += __shfl_xor(cl,m,64); }
    if (lane==0){ wcnt[wv]=cm; wlt[wv]=cl; }
    __syncthreads();
    int base = wlt[0]+wlt[1]+wlt[2]+wlt[3];     // #{key < target} over all E
    int wstart = base;
    for (int i=0;i<wv;++i) wstart += wcnt[i];   // + matches in earlier quarters
    // pass 2: stable ballot compaction within the quarter
    unsigned long long ltmask = (1ull<<lane) - 1ull;
    int carry = 0;
    for (int wq=0; wq<32; ++wq){
      int e = q0 + wq*64 + lane;
      bool mm = (key[e]==target);
      unsigned long long bal = __ballot(mm);
      if (mm) outl[wstart + carry + __popcll(bal & ltmask)] = e;
      carry += __popcll(bal);
    }
    if (t==0){
      int tot = wcnt[0]+wcnt[1]+wcnt[2]+wcnt[3];
      if (seg<NN){ ncnt[seg]=tot; noff[seg]=base; }
      else       { ecnt[seg-NN]=tot; eoff[seg-NN]=base; }
    }
    return;
  }

  // ---- gemm: register-tiled 4x4, LDS-staged X(+pad)/W; fuses natt1 + rsBN
  size_t rbase = (size_t)(bid - NSEG)*64;
  {
    const float4* xs = (const float4*)(x + rbase*CC);
    const float4* wsrc = (const float4*)w;
    #pragma unroll
    for (int i=0;i<4;++i){
      int idx = t + i*256;
      int r = idx>>4, c4 = idx&15;
      float4 v = xs[idx];
      *(float4*)&Xl[r*68 + c4*4] = v;
      ((float4*)Wl)[idx] = wsrc[idx];
    }
  }
  __syncthreads();
  int rg = t>>4, cg = t&15;
  int c0 = cg*4;
  float acc[4][4];
  #pragma unroll
  for (int i=0;i<4;++i){ acc[i][0]=0.f; acc[i][1]=0.f; acc[i][2]=0.f; acc[i][3]=0.f; }
  #pragma unroll
  for (int ks=0; ks<16; ++ks){
    int k0 = ks*4;
    float4 Wf0 = *(const float4*)&Wl[(k0+0)*64 + c0];
    float4 Wf1 = *(const float4*)&Wl[(k0+1)*64 + c0];
    float4 Wf2 = *(const float4*)&Wl[(k0+2)*64 + c0];
    float4 Wf3 = *(const float4*)&Wl[(k0+3)*64 + c0];
    #pragma unroll
    for (int ri=0;ri<4;++ri){
      float4 Xf = *(const float4*)&Xl[(rg*4+ri)*68 + k0];
      acc[ri][0] += Xf.x*Wf0.x; acc[ri][1] += Xf.x*Wf0.y; acc[ri][2] += Xf.x*Wf0.z; acc[ri][3] += Xf.x*Wf0.w;
      acc[ri][0] += Xf.y*Wf1.x; acc[ri][1] += Xf.y*Wf1.y; acc[ri][2] += Xf.y*Wf1.z; acc[ri][3] += Xf.y*Wf1.w;
      acc[ri][0] += Xf.z*Wf2.x; acc[ri][1] += Xf.z*Wf2.y; acc[ri][2] += Xf.z*Wf2.z; acc[ri][3] += Xf.z*Wf2.w;
      acc[ri][0] += Xf.w*Wf3.x; acc[ri][1] += Xf.w*Wf3.y; acc[ri][2] += Xf.w*Wf3.z; acc[ri][3] += Xf.w*Wf3.w;
    }
  }
  #pragma unroll
  for (int ri=0;ri<4;++ri){
    size_t row = rbase + rg*4 + ri;
    *(float4*)&outf[row*CC + c0] = make_float4(acc[ri][0],acc[ri][1],acc[ri][2],acc[ri][3]);
  }
  float4 at1 = *(const float4*)(att + c0);
  #pragma unroll
  for (int ri=0;ri<4;++ri){
    float a1 = acc[ri][0]*at1.x + acc[ri][1]*at1.y + acc[ri][2]*at1.z + acc[ri][3]*at1.w;
    float rs = (acc[ri][0]+acc[ri][1]) + (acc[ri][2]+acc[ri][3]);
    #pragma unroll
    for (int m=8;m>=1;m>>=1){
      a1 += __shfl_xor(a1,m,64);
      rs += __shfl_xor(rs,m,64);
    }
    if (cg==0){
      size_t row = rbase + rg*4 + ri;
      int b = (int)(row>>11), n = (int)(row&(NN-1));
      natt1[n*BB+b]=a1; rsBN[row]=rs;
    }
  }
}

// ================= K2: [es/nrm/eatt2/gpart3 (200) || gpart2 partials (32)] =======
__global__ __launch_bounds__(256) void k_es(
    const int* __restrict__ elist,const int* __restrict__ eoff,
    const int* __restrict__ ecnt,const int* __restrict__ nidx,
    const float* __restrict__ outf,const float* __restrict__ att,
    float* __restrict__ es,float* __restrict__ nrm,float* __restrict__ eatt2,
    float* __restrict__ gpart3,
    const float* __restrict__ rsBN,const int* __restrict__ ncnt,
    float* __restrict__ gpart2){
  __shared__ int lds_n[ETILE];
  __shared__ float red2[256];
  int bid = blockIdx.x, t = threadIdx.x;

  if (bid >= MM*4){
    int k = bid - MM*4;
    float s = 0.f;
    for (int i=k*256+t; i<NN*BB; i+=32*256) s += rsBN[i]*(float)ncnt[i&(NN-1)];
    red2[t]=s; __syncthreads();
    for (int st=128;st>0;st>>=1){ if(t<st) red2[t]+=red2[t+st]; __syncthreads(); }
    if (t==0) gpart2[k]=red2[0];
    return;
  }

  int m = bid>>2, bq = bid&3;
  int bi = t>>4;
  int b  = bq*16 + bi;
  int c0 = (t&15)*4;
  int off = eoff[m], deg = ecnt[m];
  float4 as=make_float4(0.f,0.f,0.f,0.f);
  for (int tb=0; tb<deg; tb+=ETILE){
    int tl = min(ETILE, deg-tb);
    __syncthreads();
    for (int j=t;j<tl;j+=256) lds_n[j]=nidx[elist[off+tb+j]];
    __syncthreads();
    #pragma unroll 4
    for (int j=0;j<tl;++j){
      int n = lds_n[j];
      float4 v = *(const float4*)&outf[(size_t)b*(NN*CC) + (size_t)n*CC + c0];
      as.x+=v.x; as.y+=v.y; as.z+=v.z; as.w+=v.w;
    }
  }
  size_t o = ((size_t)m*BB+b)*CC+c0;
  *(float4*)&es[o]=as;
  float ssq = as.x*as.x+as.y*as.y+as.z*as.z+as.w*as.w;
  float4 at2 = *(const float4*)(att + CC + c0);
  float ea = as.x*at2.x+as.y*at2.y+as.z*at2.z+as.w*at2.w;
  #pragma unroll
  for (int s=8;s>=1;s>>=1){ ssq += __shfl_xor(ssq,s,64); ea += __shfl_xor(ea,s,64); }
  if ((t&15)==0){
    nrm[m*BB+b] = ssq>0.f? sqrtf(ssq):0.f;
    eatt2[m*BB+b] = ea;
  }
  red2[t] = (as.x+as.y)+(as.z+as.w);
  __syncthreads();
  for (int s=128;s>0;s>>=1){ if(t<s) red2[t]+=red2[t+s]; __syncthreads(); }
  if (t==0) gpart3[bid] = red2[0]*(float)deg;
}

// ================= K3: [pair (625) || alpha (512 x 4 waves)] =====================
__global__ __launch_bounds__(256) void k_ap(
    const float* __restrict__ es,const float* __restrict__ nrm,
    float* __restrict__ pairl,
    const int* __restrict__ nlist,const int* __restrict__ noff,
    const int* __restrict__ ncnt,const int* __restrict__ eidx,
    const float* __restrict__ natt1,const float* __restrict__ eatt2,
    float* __restrict__ alpha){
  int bid = blockIdx.x, t = threadIdx.x;
  int wv = t>>6, b = t&63;

  if (bid < NPAIRBLK){
    int km = bid*4 + wv;
    if (km >= MM*MM) return;
    int kk = km / MM, m = km % MM;
    const float4* pa = (const float4*)&es[((size_t)kk*BB+b)*CC];
    const float4* pb = (const float4*)&es[((size_t)m*BB+b)*CC];
    float inner=0.f, d2=0.f;
    #pragma unroll
    for (int q=0;q<16;++q){
      float4 a=pa[q], c=pb[q];
      inner += a.x*c.x+a.y*c.y+a.z*c.z+a.w*c.w;
      float dx=a.x-c.x, dy=a.y-c.y, dz=a.z-c.z, dw=a.w-c.w;
      d2 += dx*dx+dy*dy+dz*dz+dw*dw;
    }
    float dist = d2>0.f? sqrtf(d2):0.f;
    float cosv = inner/(nrm[kk*BB+b]*nrm[m*BB+b]);
    float li = cosv*dist + (1.f-cosv)*fmaxf(MARGIN_-dist,0.f);
    #pragma unroll
    for (int s=32;s>=1;s>>=1) li += __shfl_xor(li,s,64);
    if (b==0) pairl[km] = fabsf(li*(1.f/64.f));
    return;
  }

  int n = (bid - NPAIRBLK)*4 + wv;
  if (n >= NN) return;
  int off = noff[n], deg = ncnt[n];
  if (deg==0) return;
  float na = natt1[n*BB+b];
  float mx = -1e30f;
  for (int j=0;j<deg;++j){
    int e = nlist[off+j]; int m = eidx[e];
    float l = na + eatt2[m*BB+b]; l = l>0.f? l : NEG*l;
    mx = fmaxf(mx,l);
  }
  float s=0.f;
  for (int j=0;j<deg;++j){
    int e = nlist[off+j]; int m = eidx[e];
    float l = na + eatt2[m*BB+b]; l = l>0.f? l : NEG*l;
    s += expf(l-mx);
  }
  float inv = 1.f/(s+1e-16f);
  for (int j=0;j<deg;++j){
    int e = nlist[off+j]; int m = eidx[e];
    float l = na + eatt2[m*BB+b]; l = l>0.f? l : NEG*l;
    alpha[(size_t)e*BB+b] = expf(l-mx)*inv;
  }
}

// ================= K4: ef = (1/deg) sum alpha * xw (alpha-weighted gather) =======
__global__ __launch_bounds__(256) void k_ef(
    const int* __restrict__ elist,const int* __restrict__ eoff,
    const int* __restrict__ ecnt,const int* __restrict__ nidx,
    const float* __restrict__ outf,const float* __restrict__ alpha,
    float* __restrict__ ef){
  __shared__ int   lds_e[ETILE];
  __shared__ int   lds_n[ETILE];
  __shared__ float lds_al[ETILE*16];
  int m = blockIdx.x>>2, bq = blockIdx.x&3;
  int t = threadIdx.x;
  int bi = t>>4;
  int b  = bq*16 + bi;
  int c0 = (t&15)*4;
  int off = eoff[m], deg = ecnt[m];
  float4 af=make_float4(0.f,0.f,0.f,0.f);
  for (int tb=0; tb<deg; tb+=ETILE){
    int tl = min(ETILE, deg-tb);
    __syncthreads();
    for (int j=t;j<tl;j+=256){
      int e = elist[off+tb+j];
      lds_e[j]=e; lds_n[j]=nidx[e];
    }
    __syncthreads();
    for (int idx=t; idx<tl*16; idx+=256){
      int j=idx>>4, b2=idx&15;
      lds_al[idx] = alpha[(size_t)lds_e[j]*BB + bq*16 + b2];
    }
    __syncthreads();
    #pragma unroll 4
    for (int j=0;j<tl;++j){
      int n = lds_n[j];
      float al = lds_al[j*16+bi];
      float4 v = *(const float4*)&outf[(size_t)b*(NN*CC) + (size_t)n*CC + c0];
      af.x+=al*v.x; af.y+=al*v.y; af.z+=al*v.z; af.w+=al*v.w;
    }
  }
  float bn = deg>0 ? 1.f/(float)deg : 0.f;
  size_t o = ((size_t)m*BB+b)*CC+c0;
  float4 f; f.x=af.x*bn; f.y=af.y*bn; f.z=af.z*bn; f.w=af.w*bn;
  *(float4*)&ef[o]=f;
}

// ================= K5: [out (2048) || lfin (block NN)] ===========================
__global__ __launch_bounds__(256) void k_outl(
    const int* __restrict__ nlist,const int* __restrict__ noff,
    const int* __restrict__ ncnt,const int* __restrict__ eidx,
    const float* __restrict__ alpha,const float* __restrict__ ef,
    const float* __restrict__ pairl,const float* __restrict__ gpart2,
    const float* __restrict__ gpart3,
    float* __restrict__ outf){
  __shared__ float r1[256],r2[256],r3[256];
  int bid = blockIdx.x, t = threadIdx.x;

  if (bid == NN){
    float s1=0.f,s2=0.f,s3=0.f;
    for (int i=t;i<MM*MM;i+=256) s1+=pairl[i];
    if (t<32) s2=gpart2[t];
    for (int i=t;i<MM*4;i+=256) s3+=gpart3[i];
    r1[t]=s1;r2[t]=s2;r3[t]=s3; __syncthreads();
    for (int s=128;s>0;s>>=1){ if(t<s){r1[t]+=r1[t+s];r2[t]+=r2[t+s];r3[t]+=r3[t+s];} __syncthreads(); }
    if (t==0){
      float lh = r1[0]/2601.f;                           // /(M+1)^2
      float con = fabsf((r2[0]-r3[0])*(1.f/33554432.f)); // /(E*B*C)
      outf[(size_t)NN*BB*CC] = con+lh;
    }
    return;
  }

  int n = bid;
  int b = t>>2, sub = t&3;
  int off = noff[n], deg = ncnt[n];
  float4 a0=make_float4(0.f,0.f,0.f,0.f),a1=a0,a2=a0,a3=a0;
  for (int j=0;j<deg;++j){
    int e = nlist[off+j]; int m = eidx[e];
    float al = alpha[(size_t)e*BB+b];
    const float4* p = (const float4*)&ef[((size_t)m*BB+b)*CC + sub*16];
    float4 v0=p[0],v1=p[1],v2=p[2],v3=p[3];
    a0.x+=al*v0.x; a0.y+=al*v0.y; a0.z+=al*v0.z; a0.w+=al*v0.w;
    a1.x+=al*v1.x; a1.y+=al*v1.y; a1.z+=al*v1.z; a1.w+=al*v1.w;
    a2.x+=al*v2.x; a2.y+=al*v2.y; a2.z+=al*v2.z; a2.w+=al*v2.w;
    a3.x+=al*v3.x; a3.y+=al*v3.y; a3.z+=al*v3.z; a3.w+=al*v3.w;
  }
  float D=(float)deg;
  float* o = &outf[(size_t)b*(NN*CC) + (size_t)n*CC + sub*16];
  ((float4*)o)[0]=make_float4(D*a0.x,D*a0.y,D*a0.z,D*a0.w);
  ((float4*)o)[1]=make_float4(D*a1.x,D*a1.y,D*a1.z,D*a1.w);
  ((float4*)o)[2]=make_float4(D*a2.x,D*a2.y,D*a2.z,D*a2.w);
  ((float4*)o)[3]=make_float4(D*a3.x,D*a3.y,D*a3.z,D*a3.w);
}

extern "C" void kernel_launch(void* const* d_in, const int* in_sizes, int n_in,
                              void* d_out, int out_size, void* d_ws, size_t ws_size,
                              hipStream_t stream){
  (void)in_sizes; (void)n_in; (void)out_size; (void)ws_size;
  const float* x    = (const float*)d_in[0];
  const float* w    = (const float*)d_in[1];
  const float* att  = (const float*)d_in[2];
  const int*   nidx = (const int*)d_in[3];
  const int*   eidx = (const int*)d_in[4];
  float* outf = (float*)d_out;

  char* ws = (char*)d_ws;
  size_t off = 0;
  auto alloc = [&](size_t bytes)->void*{ void* p = ws + off; off = (off + bytes + 255) & ~(size_t)255; return p; };
  float* natt1 = (float*)alloc(sizeof(float)*NN*BB);
  float* eatt2 = (float*)alloc(sizeof(float)*MM*BB);
  float* alpha = (float*)alloc(sizeof(float)*(size_t)EE*BB);
  float* es    = (float*)alloc(sizeof(float)*MM*BB*CC);
  float* ef    = (float*)alloc(sizeof(float)*MM*BB*CC);
  float* nrm   = (float*)alloc(sizeof(float)*MM*BB);
  float* pairl = (float*)alloc(sizeof(float)*MM*MM);
  float* rsBN  = (float*)alloc(sizeof(float)*NN*BB);
  float* gpart2= (float*)alloc(sizeof(float)*32);
  float* gpart3= (float*)alloc(sizeof(float)*MM*4);
  int* ncnt = (int*)alloc(sizeof(int)*NN);
  int* noff = (int*)alloc(sizeof(int)*NN);
  int* ecnt = (int*)alloc(sizeof(int)*MM);
  int* eoff = (int*)alloc(sizeof(int)*MM);
  int* nlist= (int*)alloc(sizeof(int)*EE);
  int* elist= (int*)alloc(sizeof(int)*EE);

  k_bg  <<<NSEG + (NN*BB)/64, 256, 0, stream>>>(x, w, att, nidx, eidx,
                                                outf, natt1, rsBN,
                                                ncnt, noff, ecnt, eoff, nlist, elist);
  k_es  <<<MM*4 + 32, 256, 0, stream>>>(elist, eoff, ecnt, nidx, outf, att,
                                        es, nrm, eatt2, gpart3, rsBN, ncnt, gpart2);
  k_ap  <<<NPAIRBLK + NN/4, 256, 0, stream>>>(es, nrm, pairl,
                                              nlist, noff, ncnt, eidx, natt1, eatt2, alpha);
  k_ef  <<<MM*4, 256, 0, stream>>>(elist, eoff, ecnt, nidx, outf, alpha, ef);
  k_outl<<<NN + 1, 256, 0, stream>>>(nlist, noff, ncnt, eidx, alpha, ef,
                                     pairl, gpart2, gpart3, outf);
}

// Round 14
// 120.235 us; speedup vs baseline: 4.5174x; 1.0661x over previous
//
#include <hip/hip_runtime.h>
#include <math.h>

#define NN 2048
#define MM 50
#define CC 64
#define BB 64
#define EE 8192
#define NEG 0.2f
#define MARGIN_ 4.2f
#define ETILE 320
#define NPAIRBLK 625      // ceil(MM*MM/4)
#define NSEG (NN+MM)      // build blocks: one per segment

// ================= K1: [CSR build (block/segment) || natt1/rsBN pass] ============
// natt1[n,b] = x_row . (W@att1);  rsBN[row] = x_row . (W@1)   (matmul-last identity)
__global__ __launch_bounds__(256) void k_bg(
    const float* __restrict__ x, const float* __restrict__ w, const float* __restrict__ att,
    const int* __restrict__ nidx, const int* __restrict__ eidx,
    float* __restrict__ natt1, float* __restrict__ rsBN,
    int* __restrict__ ncnt, int* __restrict__ noff, int* __restrict__ ecnt,
    int* __restrict__ eoff, int* __restrict__ nlist, int* __restrict__ elist){
  __shared__ int wcnt[4], wlt[4];
  __shared__ float wa[64], wo[64];
  int t = threadIdx.x;
  int bid = blockIdx.x;

  if (bid < NSEG){
    // ---- build: one block per segment; each wave scans a 2048-elem quarter of E.
    int seg = bid;
    const int* key; int target; int* outl;
    if (seg < NN){ key=nidx; target=seg;    outl=nlist; }
    else         { key=eidx; target=seg-NN; outl=elist; }
    int wv=t>>6, lane=t&63;
    int q0 = wv*2048;
    int cm=0, cl=0;
    for (int i=lane; i<2048; i+=64){
      int k = key[q0+i];
      cm += (k==target); cl += (k<target);
    }
    #pragma unroll
    for (int m=32;m>=1;m>>=1){ cm += __shfl_xor(cm,m,64); cl += __shfl_xor(cl,m,64); }
    if (lane==0){ wcnt[wv]=cm; wlt[wv]=cl; }
    __syncthreads();
    int base = wlt[0]+wlt[1]+wlt[2]+wlt[3];
    int wstart = base;
    for (int i=0;i<wv;++i) wstart += wcnt[i];
    unsigned long long ltmask = (1ull<<lane) - 1ull;
    int carry = 0;
    for (int wq=0; wq<32; ++wq){
      int e = q0 + wq*64 + lane;
      bool mm = (key[e]==target);
      unsigned long long bal = __ballot(mm);
      if (mm) outl[wstart + carry + __popcll(bal & ltmask)] = e;
      carry += __popcll(bal);
    }
    if (t==0){
      int tot = wcnt[0]+wcnt[1]+wcnt[2]+wcnt[3];
      if (seg<NN){ ncnt[seg]=tot; noff[seg]=base; }
      else       { ecnt[seg-NN]=tot; eoff[seg-NN]=base; }
    }
    return;
  }

  // ---- natt pass: 64 rows/block; wa = W@att1, wo = W@1 computed in-block
  if (t < 64){
    float sa=0.f, so=0.f;
    const float4* wr = (const float4*)(w + t*CC);
    #pragma unroll
    for (int i=0;i<16;++i){
      float4 wv = wr[i];
      float4 a1 = *(const float4*)(att + i*4);
      sa += wv.x*a1.x + wv.y*a1.y + wv.z*a1.z + wv.w*a1.w;
      so += (wv.x+wv.y)+(wv.z+wv.w);
    }
    wa[t]=sa; wo[t]=so;
  }
  __syncthreads();
  size_t rbase = (size_t)(bid - NSEG)*64;
  int r = t>>2, q = t&3;
  size_t row = rbase + r;
  const float4* xr = (const float4*)(x + row*CC);
  float s1=0.f, s2=0.f;
  #pragma unroll
  for (int i=0;i<4;++i){
    float4 xv = xr[q*4+i];
    float4 av = *(const float4*)&wa[q*16+i*4];
    float4 ov = *(const float4*)&wo[q*16+i*4];
    s1 += xv.x*av.x + xv.y*av.y + xv.z*av.z + xv.w*av.w;
    s2 += xv.x*ov.x + xv.y*ov.y + xv.z*ov.z + xv.w*ov.w;
  }
  #pragma unroll
  for (int m=1;m<=2;m<<=1){ s1 += __shfl_xor(s1,m,64); s2 += __shfl_xor(s2,m,64); }
  if (q==0){
    int b = (int)(row>>11), n = (int)(row&(NN-1));
    natt1[n*BB+b]=s1; rsBN[row]=s2;
  }
}

// ================= K2: [xsum gather + es=xsum@W + nrm/eatt2/gpart3 || gpart2] ====
__global__ __launch_bounds__(256) void k_es(
    const int* __restrict__ elist,const int* __restrict__ eoff,
    const int* __restrict__ ecnt,const int* __restrict__ nidx,
    const float* __restrict__ x,const float* __restrict__ w,const float* __restrict__ att,
    float* __restrict__ es,float* __restrict__ nrm,float* __restrict__ eatt2,
    float* __restrict__ gpart3,
    const float* __restrict__ rsBN,const int* __restrict__ ncnt,
    float* __restrict__ gpart2){
  __shared__ int lds_n[ETILE];
  __shared__ float red2[256];
  __shared__ float Wl[4096];
  __shared__ float xsl[16*68];
  int bid = blockIdx.x, t = threadIdx.x;

  if (bid >= MM*4){
    int k = bid - MM*4;
    float s = 0.f;
    for (int i=k*256+t; i<NN*BB; i+=32*256) s += rsBN[i]*(float)ncnt[i&(NN-1)];
    red2[t]=s; __syncthreads();
    for (int st=128;st>0;st>>=1){ if(t<st) red2[t]+=red2[t+st]; __syncthreads(); }
    if (t==0) gpart2[k]=red2[0];
    return;
  }

  int m = bid>>2, bq = bid&3;
  int bi = t>>4;
  int b  = bq*16 + bi;
  int c0 = (t&15)*4;
  int off = eoff[m], deg = ecnt[m];
  // stage W
  {
    const float4* wsrc = (const float4*)w;
    #pragma unroll
    for (int i=0;i<4;++i) ((float4*)Wl)[t + i*256] = wsrc[t + i*256];
  }
  // gather xsum (raw x rows)
  float4 as=make_float4(0.f,0.f,0.f,0.f);
  for (int tb=0; tb<deg; tb+=ETILE){
    int tl = min(ETILE, deg-tb);
    __syncthreads();
    for (int j=t;j<tl;j+=256) lds_n[j]=nidx[elist[off+tb+j]];
    __syncthreads();
    #pragma unroll 4
    for (int j=0;j<tl;++j){
      int n = lds_n[j];
      float4 v = *(const float4*)&x[((size_t)b*NN + n)*CC + c0];
      as.x+=v.x; as.y+=v.y; as.z+=v.z; as.w+=v.w;
    }
  }
  __syncthreads();
  *(float4*)&xsl[bi*68 + c0] = as;
  __syncthreads();
  // es = xsum @ W
  float4 e4 = make_float4(0.f,0.f,0.f,0.f);
  #pragma unroll 8
  for (int k=0;k<64;++k){
    float xv = xsl[bi*68 + k];
    float4 wv = *(const float4*)&Wl[k*64 + c0];
    e4.x += xv*wv.x; e4.y += xv*wv.y; e4.z += xv*wv.z; e4.w += xv*wv.w;
  }
  size_t o = ((size_t)m*BB+b)*CC+c0;
  *(float4*)&es[o]=e4;
  float ssq = e4.x*e4.x+e4.y*e4.y+e4.z*e4.z+e4.w*e4.w;
  float4 at2 = *(const float4*)(att + CC + c0);
  float ea = e4.x*at2.x+e4.y*at2.y+e4.z*at2.z+e4.w*at2.w;
  #pragma unroll
  for (int s=8;s>=1;s>>=1){ ssq += __shfl_xor(ssq,s,64); ea += __shfl_xor(ea,s,64); }
  if ((t&15)==0){
    nrm[m*BB+b] = ssq>0.f? sqrtf(ssq):0.f;
    eatt2[m*BB+b] = ea;
  }
  red2[t] = (e4.x+e4.y)+(e4.z+e4.w);
  __syncthreads();
  for (int s=128;s>0;s>>=1){ if(t<s) red2[t]+=red2[t+s]; __syncthreads(); }
  if (t==0) gpart3[bid] = red2[0]*(float)deg;
}

// ================= K3: [pair (625) || alpha (512 x 4 waves)] =====================
__global__ __launch_bounds__(256) void k_ap(
    const float* __restrict__ es,const float* __restrict__ nrm,
    float* __restrict__ pairl,
    const int* __restrict__ nlist,const int* __restrict__ noff,
    const int* __restrict__ ncnt,const int* __restrict__ eidx,
    const float* __restrict__ natt1,const float* __restrict__ eatt2,
    float* __restrict__ alpha){
  int bid = blockIdx.x, t = threadIdx.x;
  int wv = t>>6, b = t&63;

  if (bid < NPAIRBLK){
    int km = bid*4 + wv;
    if (km >= MM*MM) return;
    int kk = km / MM, m = km % MM;
    const float4* pa = (const float4*)&es[((size_t)kk*BB+b)*CC];
    const float4* pb = (const float4*)&es[((size_t)m*BB+b)*CC];
    float inner=0.f, d2=0.f;
    #pragma unroll
    for (int q=0;q<16;++q){
      float4 a=pa[q], c=pb[q];
      inner += a.x*c.x+a.y*c.y+a.z*c.z+a.w*c.w;
      float dx=a.x-c.x, dy=a.y-c.y, dz=a.z-c.z, dw=a.w-c.w;
      d2 += dx*dx+dy*dy+dz*dz+dw*dw;
    }
    float dist = d2>0.f? sqrtf(d2):0.f;
    float cosv = inner/(nrm[kk*BB+b]*nrm[m*BB+b]);
    float li = cosv*dist + (1.f-cosv)*fmaxf(MARGIN_-dist,0.f);
    #pragma unroll
    for (int s=32;s>=1;s>>=1) li += __shfl_xor(li,s,64);
    if (b==0) pairl[km] = fabsf(li*(1.f/64.f));
    return;
  }

  int n = (bid - NPAIRBLK)*4 + wv;
  if (n >= NN) return;
  int off = noff[n], deg = ncnt[n];
  if (deg==0) return;
  float na = natt1[n*BB+b];
  float mx = -1e30f;
  for (int j=0;j<deg;++j){
    int e = nlist[off+j]; int m = eidx[e];
    float l = na + eatt2[m*BB+b]; l = l>0.f? l : NEG*l;
    mx = fmaxf(mx,l);
  }
  float s=0.f;
  for (int j=0;j<deg;++j){
    int e = nlist[off+j]; int m = eidx[e];
    float l = na + eatt2[m*BB+b]; l = l>0.f? l : NEG*l;
    s += expf(l-mx);
  }
  float inv = 1.f/(s+1e-16f);
  for (int j=0;j<deg;++j){
    int e = nlist[off+j]; int m = eidx[e];
    float l = na + eatt2[m*BB+b]; l = l>0.f? l : NEG*l;
    alpha[(size_t)e*BB+b] = expf(l-mx)*inv;
  }
}

// ================= K4: afsum gather (alpha-weighted x) + ef = afsum@W/deg ========
__global__ __launch_bounds__(256) void k_ef(
    const int* __restrict__ elist,const int* __restrict__ eoff,
    const int* __restrict__ ecnt,const int* __restrict__ nidx,
    const float* __restrict__ x,const float* __restrict__ w,
    const float* __restrict__ alpha,
    float* __restrict__ ef){
  __shared__ int   lds_e[ETILE];
  __shared__ int   lds_n[ETILE];
  __shared__ float lds_al[ETILE*16];
  __shared__ float Wl[4096];
  __shared__ float xsl[16*68];
  int m = blockIdx.x>>2, bq = blockIdx.x&3;
  int t = threadIdx.x;
  int bi = t>>4;
  int b  = bq*16 + bi;
  int c0 = (t&15)*4;
  int off = eoff[m], deg = ecnt[m];
  {
    const float4* wsrc = (const float4*)w;
    #pragma unroll
    for (int i=0;i<4;++i) ((float4*)Wl)[t + i*256] = wsrc[t + i*256];
  }
  float4 af=make_float4(0.f,0.f,0.f,0.f);
  for (int tb=0; tb<deg; tb+=ETILE){
    int tl = min(ETILE, deg-tb);
    __syncthreads();
    for (int j=t;j<tl;j+=256){
      int e = elist[off+tb+j];
      lds_e[j]=e; lds_n[j]=nidx[e];
    }
    __syncthreads();
    for (int idx=t; idx<tl*16; idx+=256){
      int j=idx>>4, b2=idx&15;
      lds_al[idx] = alpha[(size_t)lds_e[j]*BB + bq*16 + b2];
    }
    __syncthreads();
    #pragma unroll 4
    for (int j=0;j<tl;++j){
      int n = lds_n[j];
      float al = lds_al[j*16+bi];
      float4 v = *(const float4*)&x[((size_t)b*NN + n)*CC + c0];
      af.x+=al*v.x; af.y+=al*v.y; af.z+=al*v.z; af.w+=al*v.w;
    }
  }
  __syncthreads();
  *(float4*)&xsl[bi*68 + c0] = af;
  __syncthreads();
  float4 e4 = make_float4(0.f,0.f,0.f,0.f);
  #pragma unroll 8
  for (int k=0;k<64;++k){
    float xv = xsl[bi*68 + k];
    float4 wv = *(const float4*)&Wl[k*64 + c0];
    e4.x += xv*wv.x; e4.y += xv*wv.y; e4.z += xv*wv.z; e4.w += xv*wv.w;
  }
  float bn = deg>0 ? 1.f/(float)deg : 0.f;
  size_t o = ((size_t)m*BB+b)*CC+c0;
  float4 f; f.x=e4.x*bn; f.y=e4.y*bn; f.z=e4.z*bn; f.w=e4.w*bn;
  *(float4*)&ef[o]=f;
}

// ================= K5: [out (2048) || lfin (block NN)] ===========================
__global__ __launch_bounds__(256) void k_outl(
    const int* __restrict__ nlist,const int* __restrict__ noff,
    const int* __restrict__ ncnt,const int* __restrict__ eidx,
    const float* __restrict__ alpha,const float* __restrict__ ef,
    const float* __restrict__ pairl,const float* __restrict__ gpart2,
    const float* __restrict__ gpart3,
    float* __restrict__ outf){
  __shared__ float r1[256],r2[256],r3[256];
  int bid = blockIdx.x, t = threadIdx.x;

  if (bid == NN){
    float s1=0.f,s2=0.f,s3=0.f;
    for (int i=t;i<MM*MM;i+=256) s1+=pairl[i];
    if (t<32) s2=gpart2[t];
    for (int i=t;i<MM*4;i+=256) s3+=gpart3[i];
    r1[t]=s1;r2[t]=s2;r3[t]=s3; __syncthreads();
    for (int s=128;s>0;s>>=1){ if(t<s){r1[t]+=r1[t+s];r2[t]+=r2[t+s];r3[t]+=r3[t+s];} __syncthreads(); }
    if (t==0){
      float lh = r1[0]/2601.f;                           // /(M+1)^2
      float con = fabsf((r2[0]-r3[0])*(1.f/33554432.f)); // /(E*B*C)
      outf[(size_t)NN*BB*CC] = con+lh;
    }
    return;
  }

  int n = bid;
  int b = t>>2, sub = t&3;
  int off = noff[n], deg = ncnt[n];
  float4 a0=make_float4(0.f,0.f,0.f,0.f),a1=a0,a2=a0,a3=a0;
  for (int j=0;j<deg;++j){
    int e = nlist[off+j]; int m = eidx[e];
    float al = alpha[(size_t)e*BB+b];
    const float4* p = (const float4*)&ef[((size_t)m*BB+b)*CC + sub*16];
    float4 v0=p[0],v1=p[1],v2=p[2],v3=p[3];
    a0.x+=al*v0.x; a0.y+=al*v0.y; a0.z+=al*v0.z; a0.w+=al*v0.w;
    a1.x+=al*v1.x; a1.y+=al*v1.y; a1.z+=al*v1.z; a1.w+=al*v1.w;
    a2.x+=al*v2.x; a2.y+=al*v2.y; a2.z+=al*v2.z; a2.w+=al*v2.w;
    a3.x+=al*v3.x; a3.y+=al*v3.y; a3.z+=al*v3.z; a3.w+=al*v3.w;
  }
  float D=(float)deg;
  float* o = &outf[(size_t)b*(NN*CC) + (size_t)n*CC + sub*16];
  ((float4*)o)[0]=make_float4(D*a0.x,D*a0.y,D*a0.z,D*a0.w);
  ((float4*)o)[1]=make_float4(D*a1.x,D*a1.y,D*a1.z,D*a1.w);
  ((float4*)o)[2]=make_float4(D*a2.x,D*a2.y,D*a2.z,D*a2.w);
  ((float4*)o)[3]=make_float4(D*a3.x,D*a3.y,D*a3.z,D*a3.w);
}

extern "C" void kernel_launch(void* const* d_in, const int* in_sizes, int n_in,
                              void* d_out, int out_size, void* d_ws, size_t ws_size,
                              hipStream_t stream){
  (void)in_sizes; (void)n_in; (void)out_size; (void)ws_size;
  const float* x    = (const float*)d_in[0];
  const float* w    = (const float*)d_in[1];
  const float* att  = (const float*)d_in[2];
  const int*   nidx = (const int*)d_in[3];
  const int*   eidx = (const int*)d_in[4];
  float* outf = (float*)d_out;

  char* ws = (char*)d_ws;
  size_t off = 0;
  auto alloc = [&](size_t bytes)->void*{ void* p = ws + off; off = (off + bytes + 255) & ~(size_t)255; return p; };
  float* natt1 = (float*)alloc(sizeof(float)*NN*BB);
  float* eatt2 = (float*)alloc(sizeof(float)*MM*BB);
  float* alpha = (float*)alloc(sizeof(float)*(size_t)EE*BB);
  float* es    = (float*)alloc(sizeof(float)*MM*BB*CC);
  float* ef    = (float*)alloc(sizeof(float)*MM*BB*CC);
  float* nrm   = (float*)alloc(sizeof(float)*MM*BB);
  float* pairl = (float*)alloc(sizeof(float)*MM*MM);
  float* rsBN  = (float*)alloc(sizeof(float)*NN*BB);
  float* gpart2= (float*)alloc(sizeof(float)*32);
  float* gpart3= (float*)alloc(sizeof(float)*MM*4);
  int* ncnt = (int*)alloc(sizeof(int)*NN);
  int* noff = (int*)alloc(sizeof(int)*NN);
  int* ecnt = (int*)alloc(sizeof(int)*MM);
  int* eoff = (int*)alloc(sizeof(int)*MM);
  int* nlist= (int*)alloc(sizeof(int)*EE);
  int* elist= (int*)alloc(sizeof(int)*EE);

  k_bg  <<<NSEG + (NN*BB)/64, 256, 0, stream>>>(x, w, att, nidx, eidx,
                                                natt1, rsBN,
                                                ncnt, noff, ecnt, eoff, nlist, elist);
  k_es  <<<MM*4 + 32, 256, 0, stream>>>(elist, eoff, ecnt, nidx, x, w, att,
                                        es, nrm, eatt2, gpart3, rsBN, ncnt, gpart2);
  k_ap  <<<NPAIRBLK + NN/4, 256, 0, stream>>>(es, nrm, pairl,
                                              nlist, noff, ncnt, eidx, natt1, eatt2, alpha);
  k_ef  <<<MM*4, 256, 0, stream>>>(elist, eoff, ecnt, nidx, x, w, alpha, ef);
  k_outl<<<NN + 1, 256, 0, stream>>>(nlist, noff, ncnt, eidx, alpha, ef,
                                     pairl, gpart2, gpart3, outf);
}

// Round 15
// 113.167 us; speedup vs baseline: 4.7995x; 1.0625x over previous
//
#include <hip/hip_runtime.h>
#include <math.h>

#define NN 2048
#define MM 50
#define CC 64
#define BB 64
#define EE 8192
#define NEG 0.2f
#define MARGIN_ 4.2f
#define ETILE 320
#define NPAIRBLK 625      // ceil(MM*MM/4)
#define NSEG (NN+MM)      // build blocks: one per segment

// ================= K1: [CSR build || natt1/rsBN + x-transpose pass] ==============
// natt1[n,b] = x_row . (W@att1);  rsBN[row] = x_row . (W@1);  xT[n][b][c] = x[b][n][c]
__global__ __launch_bounds__(256) void k_bg(
    const float* __restrict__ x, const float* __restrict__ w, const float* __restrict__ att,
    const int* __restrict__ nidx, const int* __restrict__ eidx,
    float* __restrict__ natt1, float* __restrict__ rsBN, float* __restrict__ xT,
    int* __restrict__ ncnt, int* __restrict__ noff, int* __restrict__ ecnt,
    int* __restrict__ eoff, int* __restrict__ nlist, int* __restrict__ elist){
  __shared__ int wcnt[4], wlt[4];
  __shared__ float wa[64], wo[64];
  int t = threadIdx.x;
  int bid = blockIdx.x;

  if (bid < NSEG){
    // ---- build: one block per segment; each wave scans a 2048-elem quarter of E.
    int seg = bid;
    const int* key; int target; int* outl;
    if (seg < NN){ key=nidx; target=seg;    outl=nlist; }
    else         { key=eidx; target=seg-NN; outl=elist; }
    int wv=t>>6, lane=t&63;
    int q0 = wv*2048;
    int cm=0, cl=0;
    for (int i=lane; i<2048; i+=64){
      int k = key[q0+i];
      cm += (k==target); cl += (k<target);
    }
    #pragma unroll
    for (int m=32;m>=1;m>>=1){ cm += __shfl_xor(cm,m,64); cl += __shfl_xor(cl,m,64); }
    if (lane==0){ wcnt[wv]=cm; wlt[wv]=cl; }
    __syncthreads();
    int base = wlt[0]+wlt[1]+wlt[2]+wlt[3];
    int wstart = base;
    for (int i=0;i<wv;++i) wstart += wcnt[i];
    unsigned long long ltmask = (1ull<<lane) - 1ull;
    int carry = 0;
    for (int wq=0; wq<32; ++wq){
      int e = q0 + wq*64 + lane;
      bool mm = (key[e]==target);
      unsigned long long bal = __ballot(mm);
      if (mm) outl[wstart + carry + __popcll(bal & ltmask)] = e;
      carry += __popcll(bal);
    }
    if (t==0){
      int tot = wcnt[0]+wcnt[1]+wcnt[2]+wcnt[3];
      if (seg<NN){ ncnt[seg]=tot; noff[seg]=base; }
      else       { ecnt[seg-NN]=tot; eoff[seg-NN]=base; }
    }
    return;
  }

  // ---- natt + transpose pass: 64 rows/block; wa = W@att1, wo = W@1 in-block
  if (t < 64){
    float sa=0.f, so=0.f;
    const float4* wr = (const float4*)(w + t*CC);
    #pragma unroll
    for (int i=0;i<16;++i){
      float4 wv = wr[i];
      float4 a1 = *(const float4*)(att + i*4);
      sa += wv.x*a1.x + wv.y*a1.y + wv.z*a1.z + wv.w*a1.w;
      so += (wv.x+wv.y)+(wv.z+wv.w);
    }
    wa[t]=sa; wo[t]=so;
  }
  __syncthreads();
  size_t rbase = (size_t)(bid - NSEG)*64;
  int r = t>>2, q = t&3;
  size_t row = rbase + r;
  int b = (int)(row>>11), n = (int)(row&(NN-1));
  const float4* xr = (const float4*)(x + row*CC);
  float4* xtrow = (float4*)(xT + ((size_t)n*BB + b)*CC);
  float s1=0.f, s2=0.f;
  #pragma unroll
  for (int i=0;i<4;++i){
    float4 xv = xr[q*4+i];
    xtrow[q*4+i] = xv;                    // xT[n][b][c] = x[b][n][c]
    float4 av = *(const float4*)&wa[q*16+i*4];
    float4 ov = *(const float4*)&wo[q*16+i*4];
    s1 += xv.x*av.x + xv.y*av.y + xv.z*av.z + xv.w*av.w;
    s2 += xv.x*ov.x + xv.y*ov.y + xv.z*ov.z + xv.w*ov.w;
  }
  #pragma unroll
  for (int m=1;m<=2;m<<=1){ s1 += __shfl_xor(s1,m,64); s2 += __shfl_xor(s2,m,64); }
  if (q==0){
    natt1[n*BB+b]=s1; rsBN[row]=s2;
  }
}

// ================= K2: [xsum gather (xT) + es=xsum@W + nrm/eatt2/gpart3 || gpart2]
__global__ __launch_bounds__(256) void k_es(
    const int* __restrict__ elist,const int* __restrict__ eoff,
    const int* __restrict__ ecnt,const int* __restrict__ nidx,
    const float* __restrict__ xT,const float* __restrict__ w,const float* __restrict__ att,
    float* __restrict__ es,float* __restrict__ nrm,float* __restrict__ eatt2,
    float* __restrict__ gpart3,
    const float* __restrict__ rsBN,const int* __restrict__ ncnt,
    float* __restrict__ gpart2){
  __shared__ int lds_n[ETILE];
  __shared__ float red2[256];
  __shared__ float Wl[4096];
  __shared__ float xsl[16*68];
  int bid = blockIdx.x, t = threadIdx.x;

  if (bid >= MM*4){
    int k = bid - MM*4;
    float s = 0.f;
    for (int i=k*256+t; i<NN*BB; i+=32*256) s += rsBN[i]*(float)ncnt[i&(NN-1)];
    red2[t]=s; __syncthreads();
    for (int st=128;st>0;st>>=1){ if(t<st) red2[t]+=red2[t+st]; __syncthreads(); }
    if (t==0) gpart2[k]=red2[0];
    return;
  }

  int m = bid>>2, bq = bid&3;
  int bi = t>>4;
  int b  = bq*16 + bi;
  int c0 = (t&15)*4;
  int off = eoff[m], deg = ecnt[m];
  {
    const float4* wsrc = (const float4*)w;
    #pragma unroll
    for (int i=0;i<4;++i) ((float4*)Wl)[t + i*256] = wsrc[t + i*256];
  }
  float4 as=make_float4(0.f,0.f,0.f,0.f);
  for (int tb=0; tb<deg; tb+=ETILE){
    int tl = min(ETILE, deg-tb);
    __syncthreads();
    for (int j=t;j<tl;j+=256) lds_n[j]=nidx[elist[off+tb+j]];
    __syncthreads();
    #pragma unroll 8
    for (int j=0;j<tl;++j){
      int n = lds_n[j];
      float4 v = *(const float4*)&xT[((size_t)n*BB + b)*CC + c0];   // contiguous 4KB/block/j
      as.x+=v.x; as.y+=v.y; as.z+=v.z; as.w+=v.w;
    }
  }
  __syncthreads();
  *(float4*)&xsl[bi*68 + c0] = as;
  __syncthreads();
  float4 e4 = make_float4(0.f,0.f,0.f,0.f);
  #pragma unroll 8
  for (int k=0;k<64;++k){
    float xv = xsl[bi*68 + k];
    float4 wv = *(const float4*)&Wl[k*64 + c0];
    e4.x += xv*wv.x; e4.y += xv*wv.y; e4.z += xv*wv.z; e4.w += xv*wv.w;
  }
  size_t o = ((size_t)m*BB+b)*CC+c0;
  *(float4*)&es[o]=e4;
  float ssq = e4.x*e4.x+e4.y*e4.y+e4.z*e4.z+e4.w*e4.w;
  float4 at2 = *(const float4*)(att + CC + c0);
  float ea = e4.x*at2.x+e4.y*at2.y+e4.z*at2.z+e4.w*at2.w;
  #pragma unroll
  for (int s=8;s>=1;s>>=1){ ssq += __shfl_xor(ssq,s,64); ea += __shfl_xor(ea,s,64); }
  if ((t&15)==0){
    nrm[m*BB+b] = ssq>0.f? sqrtf(ssq):0.f;
    eatt2[m*BB+b] = ea;
  }
  red2[t] = (e4.x+e4.y)+(e4.z+e4.w);
  __syncthreads();
  for (int s=128;s>0;s>>=1){ if(t<s) red2[t]+=red2[t+s]; __syncthreads(); }
  if (t==0) gpart3[bid] = red2[0]*(float)deg;
}

// ================= K3: [pair (625) || alpha (512 x 4 waves)] =====================
__global__ __launch_bounds__(256) void k_ap(
    const float* __restrict__ es,const float* __restrict__ nrm,
    float* __restrict__ pairl,
    const int* __restrict__ nlist,const int* __restrict__ noff,
    const int* __restrict__ ncnt,const int* __restrict__ eidx,
    const float* __restrict__ natt1,const float* __restrict__ eatt2,
    float* __restrict__ alpha){
  int bid = blockIdx.x, t = threadIdx.x;
  int wv = t>>6, b = t&63;

  if (bid < NPAIRBLK){
    int km = bid*4 + wv;
    if (km >= MM*MM) return;
    int kk = km / MM, m = km % MM;
    const float4* pa = (const float4*)&es[((size_t)kk*BB+b)*CC];
    const float4* pb = (const float4*)&es[((size_t)m*BB+b)*CC];
    float inner=0.f, d2=0.f;
    #pragma unroll
    for (int q=0;q<16;++q){
      float4 a=pa[q], c=pb[q];
      inner += a.x*c.x+a.y*c.y+a.z*c.z+a.w*c.w;
      float dx=a.x-c.x, dy=a.y-c.y, dz=a.z-c.z, dw=a.w-c.w;
      d2 += dx*dx+dy*dy+dz*dz+dw*dw;
    }
    float dist = d2>0.f? sqrtf(d2):0.f;
    float cosv = inner/(nrm[kk*BB+b]*nrm[m*BB+b]);
    float li = cosv*dist + (1.f-cosv)*fmaxf(MARGIN_-dist,0.f);
    #pragma unroll
    for (int s=32;s>=1;s>>=1) li += __shfl_xor(li,s,64);
    if (b==0) pairl[km] = fabsf(li*(1.f/64.f));
    return;
  }

  int n = (bid - NPAIRBLK)*4 + wv;
  if (n >= NN) return;
  int off = noff[n], deg = ncnt[n];
  if (deg==0) return;
  float na = natt1[n*BB+b];
  float mx = -1e30f;
  for (int j=0;j<deg;++j){
    int e = nlist[off+j]; int m = eidx[e];
    float l = na + eatt2[m*BB+b]; l = l>0.f? l : NEG*l;
    mx = fmaxf(mx,l);
  }
  float s=0.f;
  for (int j=0;j<deg;++j){
    int e = nlist[off+j]; int m = eidx[e];
    float l = na + eatt2[m*BB+b]; l = l>0.f? l : NEG*l;
    s += expf(l-mx);
  }
  float inv = 1.f/(s+1e-16f);
  for (int j=0;j<deg;++j){
    int e = nlist[off+j]; int m = eidx[e];
    float l = na + eatt2[m*BB+b]; l = l>0.f? l : NEG*l;
    alpha[(size_t)e*BB+b] = expf(l-mx)*inv;
  }
}

// ================= K4: afsum gather (alpha-weighted xT) + ef = afsum@W/deg =======
__global__ __launch_bounds__(256) void k_ef(
    const int* __restrict__ elist,const int* __restrict__ eoff,
    const int* __restrict__ ecnt,const int* __restrict__ nidx,
    const float* __restrict__ xT,const float* __restrict__ w,
    const float* __restrict__ alpha,
    float* __restrict__ ef){
  __shared__ int   lds_e[ETILE];
  __shared__ int   lds_n[ETILE];
  __shared__ float lds_al[ETILE*16];
  __shared__ float Wl[4096];
  __shared__ float xsl[16*68];
  int m = blockIdx.x>>2, bq = blockIdx.x&3;
  int t = threadIdx.x;
  int bi = t>>4;
  int b  = bq*16 + bi;
  int c0 = (t&15)*4;
  int off = eoff[m], deg = ecnt[m];
  {
    const float4* wsrc = (const float4*)w;
    #pragma unroll
    for (int i=0;i<4;++i) ((float4*)Wl)[t + i*256] = wsrc[t + i*256];
  }
  float4 af=make_float4(0.f,0.f,0.f,0.f);
  for (int tb=0; tb<deg; tb+=ETILE){
    int tl = min(ETILE, deg-tb);
    __syncthreads();
    for (int j=t;j<tl;j+=256){
      int e = elist[off+tb+j];
      lds_e[j]=e; lds_n[j]=nidx[e];
    }
    __syncthreads();
    for (int idx=t; idx<tl*16; idx+=256){
      int j=idx>>4, b2=idx&15;
      lds_al[idx] = alpha[(size_t)lds_e[j]*BB + bq*16 + b2];
    }
    __syncthreads();
    #pragma unroll 8
    for (int j=0;j<tl;++j){
      int n = lds_n[j];
      float al = lds_al[j*16+bi];
      float4 v = *(const float4*)&xT[((size_t)n*BB + b)*CC + c0];   // contiguous 4KB/block/j
      af.x+=al*v.x; af.y+=al*v.y; af.z+=al*v.z; af.w+=al*v.w;
    }
  }
  __syncthreads();
  *(float4*)&xsl[bi*68 + c0] = af;
  __syncthreads();
  float4 e4 = make_float4(0.f,0.f,0.f,0.f);
  #pragma unroll 8
  for (int k=0;k<64;++k){
    float xv = xsl[bi*68 + k];
    float4 wv = *(const float4*)&Wl[k*64 + c0];
    e4.x += xv*wv.x; e4.y += xv*wv.y; e4.z += xv*wv.z; e4.w += xv*wv.w;
  }
  float bn = deg>0 ? 1.f/(float)deg : 0.f;
  size_t o = ((size_t)m*BB+b)*CC+c0;
  float4 f; f.x=e4.x*bn; f.y=e4.y*bn; f.z=e4.z*bn; f.w=e4.w*bn;
  *(float4*)&ef[o]=f;
}

// ================= K5: [out (2048) || lfin (block NN)] ===========================
__global__ __launch_bounds__(256) void k_outl(
    const int* __restrict__ nlist,const int* __restrict__ noff,
    const int* __restrict__ ncnt,const int* __restrict__ eidx,
    const float* __restrict__ alpha,const float* __restrict__ ef,
    const float* __restrict__ pairl,const float* __restrict__ gpart2,
    const float* __restrict__ gpart3,
    float* __restrict__ outf){
  __shared__ float r1[256],r2[256],r3[256];
  int bid = blockIdx.x, t = threadIdx.x;

  if (bid == NN){
    float s1=0.f,s2=0.f,s3=0.f;
    for (int i=t;i<MM*MM;i+=256) s1+=pairl[i];
    if (t<32) s2=gpart2[t];
    for (int i=t;i<MM*4;i+=256) s3+=gpart3[i];
    r1[t]=s1;r2[t]=s2;r3[t]=s3; __syncthreads();
    for (int s=128;s>0;s>>=1){ if(t<s){r1[t]+=r1[t+s];r2[t]+=r2[t+s];r3[t]+=r3[t+s];} __syncthreads(); }
    if (t==0){
      float lh = r1[0]/2601.f;                           // /(M+1)^2
      float con = fabsf((r2[0]-r3[0])*(1.f/33554432.f)); // /(E*B*C)
      outf[(size_t)NN*BB*CC] = con+lh;
    }
    return;
  }

  int n = bid;
  int b = t>>2, sub = t&3;
  int off = noff[n], deg = ncnt[n];
  float4 a0=make_float4(0.f,0.f,0.f,0.f),a1=a0,a2=a0,a3=a0;
  for (int j=0;j<deg;++j){
    int e = nlist[off+j]; int m = eidx[e];
    float al = alpha[(size_t)e*BB+b];
    const float4* p = (const float4*)&ef[((size_t)m*BB+b)*CC + sub*16];
    float4 v0=p[0],v1=p[1],v2=p[2],v3=p[3];
    a0.x+=al*v0.x; a0.y+=al*v0.y; a0.z+=al*v0.z; a0.w+=al*v0.w;
    a1.x+=al*v1.x; a1.y+=al*v1.y; a1.z+=al*v1.z; a1.w+=al*v1.w;
    a2.x+=al*v2.x; a2.y+=al*v2.y; a2.z+=al*v2.z; a2.w+=al*v2.w;
    a3.x+=al*v3.x; a3.y+=al*v3.y; a3.z+=al*v3.z; a3.w+=al*v3.w;
  }
  float D=(float)deg;
  float* o = &outf[(size_t)b*(NN*CC) + (size_t)n*CC + sub*16];
  ((float4*)o)[0]=make_float4(D*a0.x,D*a0.y,D*a0.z,D*a0.w);
  ((float4*)o)[1]=make_float4(D*a1.x,D*a1.y,D*a1.z,D*a1.w);
  ((float4*)o)[2]=make_float4(D*a2.x,D*a2.y,D*a2.z,D*a2.w);
  ((float4*)o)[3]=make_float4(D*a3.x,D*a3.y,D*a3.z,D*a3.w);
}

extern "C" void kernel_launch(void* const* d_in, const int* in_sizes, int n_in,
                              void* d_out, int out_size, void* d_ws, size_t ws_size,
                              hipStream_t stream){
  (void)in_sizes; (void)n_in; (void)out_size; (void)ws_size;
  const float* x    = (const float*)d_in[0];
  const float* w    = (const float*)d_in[1];
  const float* att  = (const float*)d_in[2];
  const int*   nidx = (const int*)d_in[3];
  const int*   eidx = (const int*)d_in[4];
  float* outf = (float*)d_out;

  char* ws = (char*)d_ws;
  size_t off = 0;
  auto alloc = [&](size_t bytes)->void*{ void* p = ws + off; off = (off + bytes + 255) & ~(size_t)255; return p; };
  float* xT    = (float*)alloc(sizeof(float)*(size_t)NN*BB*CC);   // [n][b][c]
  float* natt1 = (float*)alloc(sizeof(float)*NN*BB);
  float* eatt2 = (float*)alloc(sizeof(float)*MM*BB);
  float* alpha = (float*)alloc(sizeof(float)*(size_t)EE*BB);
  float* es    = (float*)alloc(sizeof(float)*MM*BB*CC);
  float* ef    = (float*)alloc(sizeof(float)*MM*BB*CC);
  float* nrm   = (float*)alloc(sizeof(float)*MM*BB);
  float* pairl = (float*)alloc(sizeof(float)*MM*MM);
  float* rsBN  = (float*)alloc(sizeof(float)*NN*BB);
  float* gpart2= (float*)alloc(sizeof(float)*32);
  float* gpart3= (float*)alloc(sizeof(float)*MM*4);
  int* ncnt = (int*)alloc(sizeof(int)*NN);
  int* noff = (int*)alloc(sizeof(int)*NN);
  int* ecnt = (int*)alloc(sizeof(int)*MM);
  int* eoff = (int*)alloc(sizeof(int)*MM);
  int* nlist= (int*)alloc(sizeof(int)*EE);
  int* elist= (int*)alloc(sizeof(int)*EE);

  k_bg  <<<NSEG + (NN*BB)/64, 256, 0, stream>>>(x, w, att, nidx, eidx,
                                                natt1, rsBN, xT,
                                                ncnt, noff, ecnt, eoff, nlist, elist);
  k_es  <<<MM*4 + 32, 256, 0, stream>>>(elist, eoff, ecnt, nidx, xT, w, att,
                                        es, nrm, eatt2, gpart3, rsBN, ncnt, gpart2);
  k_ap  <<<NPAIRBLK + NN/4, 256, 0, stream>>>(es, nrm, pairl,
                                              nlist, noff, ncnt, eidx, natt1, eatt2, alpha);
  k_ef  <<<MM*4, 256, 0, stream>>>(elist, eoff, ecnt, nidx, xT, w, alpha, ef);
  k_outl<<<NN + 1, 256, 0, stream>>>(nlist, noff, ncnt, eidx, alpha, ef,
                                     pairl, gpart2, gpart3, outf);
}